// Round 6
// baseline (1957.117 us; speedup 1.0000x reference)
//
#include <hip/hip_runtime.h>
#include <cstdint>

#define NOUTC 131072
#define NINC  16384

using uint = unsigned int;

__device__ __forceinline__ uint fkey(float v){
  uint u = __float_as_uint(v);
  return (u & 0x80000000u) ? ~u : (u | 0x80000000u);
}

// ---------------------------------------------------------------------------
// c0: 64->64, 27 taps. Block = 64 rows x 4 waves (wave gu owns couts
// [16gu,16gu+16)). Per tap: coalesced-stage 64 gathered rows (stride 68,
// bank-balanced) + the full 16KB W[k] slab into LDS; weights read as
// wave-uniform ds_read_b128 broadcasts (no scalar stream, no conflicts).
// Single-buffered, 2 barriers/tap; next-tap global loads issued between
// barrier1 and compute so latency hides under the 2048-cy FMA burst.
// ---------------------------------------------------------------------------
__global__ __launch_bounds__(256)
void conv_c0_v4(const float* __restrict__ feats, const int* __restrict__ nbr,
                const float* __restrict__ Wc0, const float* __restrict__ bias,
                float* __restrict__ outp)
{
  __shared__ float fbuf[64 * 68];
  __shared__ float wbuf[4096];
  const int t    = threadIdx.x;
  const int gu   = __builtin_amdgcn_readfirstlane(t >> 6);
  const int lane = t & 63;
  const int base = blockIdx.x * 64;
  const int sr   = t >> 2;
  const int sq   = t & 3;

  float acc[16];
  #pragma unroll
  for (int i = 0; i < 16; ++i) acc[i] = 0.f;

  float4 fg0, fg1, fg2, fg3, wg0, wg1, wg2, wg3;
  {
    int idx = nbr[base + sr];
    const float4* fsrc = reinterpret_cast<const float4*>(feats + (size_t)idx * 64 + sq * 16);
    fg0 = fsrc[0]; fg1 = fsrc[1]; fg2 = fsrc[2]; fg3 = fsrc[3];
    const float4* wsrc = reinterpret_cast<const float4*>(Wc0);
    wg0 = wsrc[t]; wg1 = wsrc[t + 256]; wg2 = wsrc[t + 512]; wg3 = wsrc[t + 768];
  }

  #pragma unroll 1
  for (int k = 0; k < 27; ++k) {
    {
      float4* fw = reinterpret_cast<float4*>(&fbuf[sr * 68 + sq * 16]);
      fw[0] = fg0; fw[1] = fg1; fw[2] = fg2; fw[3] = fg3;
      float4* ww = reinterpret_cast<float4*>(wbuf);
      ww[t] = wg0; ww[t + 256] = wg1; ww[t + 512] = wg2; ww[t + 768] = wg3;
    }
    __syncthreads();
    if (k < 26) {
      int idx = nbr[(size_t)(k + 1) * NOUTC + base + sr];
      const float4* fsrc = reinterpret_cast<const float4*>(feats + (size_t)idx * 64 + sq * 16);
      fg0 = fsrc[0]; fg1 = fsrc[1]; fg2 = fsrc[2]; fg3 = fsrc[3];
      const float4* wsrc = reinterpret_cast<const float4*>(Wc0 + (size_t)(k + 1) * 4096);
      wg0 = wsrc[t]; wg1 = wsrc[t + 256]; wg2 = wsrc[t + 512]; wg3 = wsrc[t + 768];
    }
    const float* fr = &fbuf[lane * 68];
    const float* wb = wbuf + gu * 16;
    #pragma unroll
    for (int c = 0; c < 16; ++c) {
      float4 f4 = *reinterpret_cast<const float4*>(fr + 4 * c);
      float fv[4] = {f4.x, f4.y, f4.z, f4.w};
      #pragma unroll
      for (int u = 0; u < 4; ++u) {
        const float4* wr = reinterpret_cast<const float4*>(wb + (4 * c + u) * 64);
        float4 w0 = wr[0], w1 = wr[1], w2 = wr[2], w3 = wr[3];
        float wv[16] = {w0.x,w0.y,w0.z,w0.w, w1.x,w1.y,w1.z,w1.w,
                        w2.x,w2.y,w2.z,w2.w, w3.x,w3.y,w3.z,w3.w};
        float f = fv[u];
        #pragma unroll
        for (int j = 0; j < 16; ++j) acc[j] = fmaf(f, wv[j], acc[j]);
      }
    }
    __syncthreads();
  }

  const int n = base + lane;
  float* dst = outp + (size_t)n * 64 + gu * 16;
  #pragma unroll
  for (int q = 0; q < 4; ++q) {
    float4 o;
    float v0 = acc[4*q+0] + bias[gu*16 + 4*q+0]; o.x = v0 > 0.f ? v0 : 0.f;
    float v1 = acc[4*q+1] + bias[gu*16 + 4*q+1]; o.y = v1 > 0.f ? v1 : 0.f;
    float v2 = acc[4*q+2] + bias[gu*16 + 4*q+2]; o.z = v2 > 0.f ? v2 : 0.f;
    float v3 = acc[4*q+3] + bias[gu*16 + 4*q+3]; o.w = v3 > 0.f ? v3 : 0.f;
    reinterpret_cast<float4*>(dst)[q] = o;
  }
}

// ---------------------------------------------------------------------------
// A: t0 = relu(spconv(cur,W00)+b00) [64->16, 27 taps]
//    t1 = relu(cur@W10+b10) (fused at identity tap k=13, W10 staged once)
// cin-split: wave gu owns ci [16gu,16gu+16), computes all 16 couts; weights
// broadcast from LDS; tree-reduce partials at the end (overlays fbuf).
// ---------------------------------------------------------------------------
__global__ __launch_bounds__(256)
void conv_A_v4(const float* __restrict__ feats, const int* __restrict__ nbr,
               const float* __restrict__ W00i, const float* __restrict__ b00i,
               const float* __restrict__ W10i, const float* __restrict__ b10i,
               float* __restrict__ t0, float* __restrict__ t1)
{
  __shared__ float fbuf[64 * 68];
  __shared__ float wbuf[1024];
  __shared__ float w10s[1024];
  const int t    = threadIdx.x;
  const int gu   = __builtin_amdgcn_readfirstlane(t >> 6);
  const int lane = t & 63;
  const int base = blockIdx.x * 64;
  const int sr   = t >> 2;
  const int sq   = t & 3;

  float acc0[16], acc1[16];
  #pragma unroll
  for (int i = 0; i < 16; ++i) { acc0[i] = 0.f; acc1[i] = 0.f; }

  // stage W10 once (published by first in-loop barrier)
  reinterpret_cast<float4*>(w10s)[t] = reinterpret_cast<const float4*>(W10i)[t];

  float4 fg0, fg1, fg2, fg3, wg0;
  {
    int idx = nbr[base + sr];
    const float4* fsrc = reinterpret_cast<const float4*>(feats + (size_t)idx * 64 + sq * 16);
    fg0 = fsrc[0]; fg1 = fsrc[1]; fg2 = fsrc[2]; fg3 = fsrc[3];
    wg0 = reinterpret_cast<const float4*>(W00i)[t];
  }

  #pragma unroll 1
  for (int k = 0; k < 27; ++k) {
    {
      float4* fw = reinterpret_cast<float4*>(&fbuf[sr * 68 + sq * 16]);
      fw[0] = fg0; fw[1] = fg1; fw[2] = fg2; fw[3] = fg3;
      reinterpret_cast<float4*>(wbuf)[t] = wg0;
    }
    __syncthreads();
    if (k < 26) {
      int idx = nbr[(size_t)(k + 1) * NOUTC + base + sr];
      const float4* fsrc = reinterpret_cast<const float4*>(feats + (size_t)idx * 64 + sq * 16);
      fg0 = fsrc[0]; fg1 = fsrc[1]; fg2 = fsrc[2]; fg3 = fsrc[3];
      wg0 = reinterpret_cast<const float4*>(W00i + (size_t)(k + 1) * 1024)[t];
    }
    const float* fr = &fbuf[lane * 68 + gu * 16];
    #pragma unroll
    for (int m = 0; m < 4; ++m) {
      float4 f4 = *reinterpret_cast<const float4*>(fr + 4 * m);
      float fv[4] = {f4.x, f4.y, f4.z, f4.w};
      #pragma unroll
      for (int u = 0; u < 4; ++u) {
        const int ci = gu * 16 + 4 * m + u;
        const float4* wr = reinterpret_cast<const float4*>(wbuf + ci * 16);
        float4 w0 = wr[0], w1 = wr[1], w2 = wr[2], w3 = wr[3];
        float wv[16] = {w0.x,w0.y,w0.z,w0.w, w1.x,w1.y,w1.z,w1.w,
                        w2.x,w2.y,w2.z,w2.w, w3.x,w3.y,w3.z,w3.w};
        float f = fv[u];
        #pragma unroll
        for (int j = 0; j < 16; ++j) acc0[j] = fmaf(f, wv[j], acc0[j]);
      }
    }
    if (k == 13) {
      #pragma unroll
      for (int m = 0; m < 4; ++m) {
        float4 f4 = *reinterpret_cast<const float4*>(fr + 4 * m);
        float fv[4] = {f4.x, f4.y, f4.z, f4.w};
        #pragma unroll
        for (int u = 0; u < 4; ++u) {
          const int ci = gu * 16 + 4 * m + u;
          const float4* wr = reinterpret_cast<const float4*>(w10s + ci * 16);
          float4 w0 = wr[0], w1 = wr[1], w2 = wr[2], w3 = wr[3];
          float wv[16] = {w0.x,w0.y,w0.z,w0.w, w1.x,w1.y,w1.z,w1.w,
                          w2.x,w2.y,w2.z,w2.w, w3.x,w3.y,w3.z,w3.w};
          float f = fv[u];
          #pragma unroll
          for (int j = 0; j < 16; ++j) acc1[j] = fmaf(f, wv[j], acc1[j]);
        }
      }
    }
    __syncthreads();
  }

  // tree reduction across the 4 cin-split waves (overlay fbuf, stride 33)
  float* red = fbuf;           // 2 slots x 64 x 33 = 4224 <= 4352
  if (gu >= 2) {
    float* d = red + (size_t)(gu - 2) * 2112 + lane * 33;
    #pragma unroll
    for (int j = 0; j < 16; ++j) { d[j] = acc0[j]; d[16 + j] = acc1[j]; }
  }
  __syncthreads();
  if (gu < 2) {
    const float* s = red + (size_t)gu * 2112 + lane * 33;
    #pragma unroll
    for (int j = 0; j < 16; ++j) { acc0[j] += s[j]; acc1[j] += s[16 + j]; }
  }
  __syncthreads();
  if (gu == 1) {
    float* d = red + lane * 33;
    #pragma unroll
    for (int j = 0; j < 16; ++j) { d[j] = acc0[j]; d[16 + j] = acc1[j]; }
  }
  __syncthreads();
  if (gu == 0) {
    const float* s = red + lane * 33;
    const int n = base + lane;
    float* d0 = t0 + (size_t)n * 16;
    float* d1 = t1 + (size_t)n * 16;
    #pragma unroll
    for (int q = 0; q < 4; ++q) {
      float4 o0, o1; float v;
      v = acc0[4*q+0] + s[4*q+0] + b00i[4*q+0]; o0.x = v > 0.f ? v : 0.f;
      v = acc0[4*q+1] + s[4*q+1] + b00i[4*q+1]; o0.y = v > 0.f ? v : 0.f;
      v = acc0[4*q+2] + s[4*q+2] + b00i[4*q+2]; o0.z = v > 0.f ? v : 0.f;
      v = acc0[4*q+3] + s[4*q+3] + b00i[4*q+3]; o0.w = v > 0.f ? v : 0.f;
      v = acc1[4*q+0] + s[16+4*q+0] + b10i[4*q+0]; o1.x = v > 0.f ? v : 0.f;
      v = acc1[4*q+1] + s[16+4*q+1] + b10i[4*q+1]; o1.y = v > 0.f ? v : 0.f;
      v = acc1[4*q+2] + s[16+4*q+2] + b10i[4*q+2]; o1.z = v > 0.f ? v : 0.f;
      v = acc1[4*q+3] + s[16+4*q+3] + b10i[4*q+3]; o1.w = v > 0.f ? v : 0.f;
      reinterpret_cast<float4*>(d0)[q] = o0;
      reinterpret_cast<float4*>(d1)[q] = o1;
    }
  }
}

// ---------------------------------------------------------------------------
// B: o0 = spconv(t0,W01)+b01 [16->32]; t2 = relu(spconv(t1,W11)+b11) [16->16];
//    o1 = t2@W12+b12; nxt = concat(o0,o1)+cur.
// Staged row = t0[16] || t1[16] (stride 36). Wave w=(a,b): ci in [8a,8a+8),
// o0 couts [16b,16b+16), t2 couts [8b,8b+8). Weights W01/W11 staged per tap,
// W12 staged once. Pair-reduce a=1 -> a=0 via rbuf, t2 broadcast, epilogue.
// ---------------------------------------------------------------------------
__global__ __launch_bounds__(256)
void conv_B_v4(const float* __restrict__ t0, const float* __restrict__ t1,
               const float* __restrict__ cur, const int* __restrict__ nbr,
               const float* __restrict__ W01i, const float* __restrict__ b01i,
               const float* __restrict__ W11i, const float* __restrict__ b11i,
               const float* __restrict__ W12i, const float* __restrict__ b12i,
               float* __restrict__ nxt)
{
  __shared__ float fbuf[64 * 36];
  __shared__ float wbuf[768];     // [0,512): W01[k], [512,768): W11[k]
  __shared__ float w12s[512];
  __shared__ float rbuf[4224];    // red [2][64][25] = 3200, t2s 1024
  const int t    = threadIdx.x;
  const int w    = __builtin_amdgcn_readfirstlane(t >> 6);
  const int a    = w >> 1, b = w & 1;
  const int lane = t & 63;
  const int base = blockIdx.x * 64;
  const int sr   = t >> 2;
  const int sq   = t & 3;

  float acc01[16], acc11[8];
  #pragma unroll
  for (int i = 0; i < 16; ++i) acc01[i] = 0.f;
  #pragma unroll
  for (int i = 0; i < 8; ++i) acc11[i] = 0.f;

  if (t < 128) reinterpret_cast<float4*>(w12s)[t] = reinterpret_cast<const float4*>(W12i)[t];

  float4 fg0, fg1, wg;
  {
    int idx = nbr[base + sr];
    fg0 = reinterpret_cast<const float4*>(t0 + (size_t)idx * 16)[sq];
    fg1 = reinterpret_cast<const float4*>(t1 + (size_t)idx * 16)[sq];
    if (t < 128)      wg = reinterpret_cast<const float4*>(W01i)[t];
    else if (t < 192) wg = reinterpret_cast<const float4*>(W11i)[t - 128];
  }

  #pragma unroll 1
  for (int k = 0; k < 27; ++k) {
    {
      float* wp = &fbuf[sr * 36 + sq * 4];
      *reinterpret_cast<float4*>(wp)      = fg0;
      *reinterpret_cast<float4*>(wp + 16) = fg1;
      if (t < 192) reinterpret_cast<float4*>(wbuf)[t] = wg;
    }
    __syncthreads();
    if (k < 26) {
      int idx = nbr[(size_t)(k + 1) * NOUTC + base + sr];
      fg0 = reinterpret_cast<const float4*>(t0 + (size_t)idx * 16)[sq];
      fg1 = reinterpret_cast<const float4*>(t1 + (size_t)idx * 16)[sq];
      if (t < 128)      wg = reinterpret_cast<const float4*>(W01i + (size_t)(k + 1) * 512)[t];
      else if (t < 192) wg = reinterpret_cast<const float4*>(W11i + (size_t)(k + 1) * 256)[t - 128];
    }
    const float* fr = &fbuf[lane * 36 + 8 * a];
    #pragma unroll
    for (int m = 0; m < 2; ++m) {
      float4 f0 = *reinterpret_cast<const float4*>(fr + 4 * m);
      float4 f1 = *reinterpret_cast<const float4*>(fr + 16 + 4 * m);
      float f0v[4] = {f0.x, f0.y, f0.z, f0.w};
      float f1v[4] = {f1.x, f1.y, f1.z, f1.w};
      #pragma unroll
      for (int u = 0; u < 4; ++u) {
        const int ci = 8 * a + 4 * m + u;
        const float4* wr01 = reinterpret_cast<const float4*>(wbuf + ci * 32 + 16 * b);
        float4 p0 = wr01[0], p1 = wr01[1], p2 = wr01[2], p3 = wr01[3];
        float pv[16] = {p0.x,p0.y,p0.z,p0.w, p1.x,p1.y,p1.z,p1.w,
                        p2.x,p2.y,p2.z,p2.w, p3.x,p3.y,p3.z,p3.w};
        float fa = f0v[u];
        #pragma unroll
        for (int j = 0; j < 16; ++j) acc01[j] = fmaf(fa, pv[j], acc01[j]);
        const float4* wr11 = reinterpret_cast<const float4*>(wbuf + 512 + ci * 16 + 8 * b);
        float4 q0 = wr11[0], q1 = wr11[1];
        float qv[8] = {q0.x,q0.y,q0.z,q0.w, q1.x,q1.y,q1.z,q1.w};
        float fb = f1v[u];
        #pragma unroll
        for (int j = 0; j < 8; ++j) acc11[j] = fmaf(fb, qv[j], acc11[j]);
      }
    }
    __syncthreads();
  }

  float* red = rbuf;              // [2][64][25]
  float* t2s = rbuf + 3200;       // [16][64]
  if (a == 1) {
    float* d = red + (size_t)b * 1600 + lane * 25;
    #pragma unroll
    for (int j = 0; j < 16; ++j) d[j] = acc01[j];
    #pragma unroll
    for (int j = 0; j < 8; ++j) d[16 + j] = acc11[j];
  }
  __syncthreads();
  if (a == 0) {
    const float* s = red + (size_t)b * 1600 + lane * 25;
    #pragma unroll
    for (int j = 0; j < 16; ++j) acc01[j] += s[j];
    #pragma unroll
    for (int j = 0; j < 8; ++j) {
      float v = acc11[j] + s[16 + j] + b11i[8 * b + j];
      t2s[(8 * b + j) * 64 + lane] = v > 0.f ? v : 0.f;
    }
  }
  __syncthreads();

  const int n = base + lane;
  float t2[16];
  #pragma unroll
  for (int u = 0; u < 16; ++u) t2[u] = t2s[u * 64 + lane];
  float o1[8];
  #pragma unroll
  for (int j = 0; j < 8; ++j) o1[j] = b12i[8 * w + j];
  #pragma unroll
  for (int u = 0; u < 16; ++u) {
    const float4* wr = reinterpret_cast<const float4*>(w12s + u * 32 + 8 * w);
    float4 q0 = wr[0], q1 = wr[1];
    float qv[8] = {q0.x,q0.y,q0.z,q0.w, q1.x,q1.y,q1.z,q1.w};
    #pragma unroll
    for (int j = 0; j < 8; ++j) o1[j] = fmaf(t2[u], qv[j], o1[j]);
  }
  {
    const float* rs = cur + (size_t)n * 64 + 32 + 8 * w;
    float* dst = nxt + (size_t)n * 64 + 32 + 8 * w;
    float4 r0 = *reinterpret_cast<const float4*>(rs);
    float4 r1 = *reinterpret_cast<const float4*>(rs + 4);
    float4 s0 = {o1[0]+r0.x, o1[1]+r0.y, o1[2]+r0.z, o1[3]+r0.w};
    float4 s1 = {o1[4]+r1.x, o1[5]+r1.y, o1[6]+r1.z, o1[7]+r1.w};
    *reinterpret_cast<float4*>(dst)     = s0;
    *reinterpret_cast<float4*>(dst + 4) = s1;
  }
  if (a == 0) {
    const float* rs = cur + (size_t)n * 64 + 16 * b;
    float* dst = nxt + (size_t)n * 64 + 16 * b;
    #pragma unroll
    for (int q = 0; q < 4; ++q) {
      float4 r = reinterpret_cast<const float4*>(rs)[q];
      float4 s;
      s.x = acc01[4*q+0] + b01i[16*b + 4*q+0] + r.x;
      s.y = acc01[4*q+1] + b01i[16*b + 4*q+1] + r.y;
      s.z = acc01[4*q+2] + b01i[16*b + 4*q+2] + r.z;
      s.w = acc01[4*q+3] + b01i[16*b + 4*q+3] + r.w;
      reinterpret_cast<float4*>(dst)[q] = s;
    }
  }
}

// ---------------------------------------------------------------------------
// upsample: fa[(n*8+k)*64+:] = relu(x[n]@Wup[k]+bup). k uniform per block,
// wave g computes couts [16g,16g+16). Scalar weights (small, L1-resident).
// ---------------------------------------------------------------------------
__global__ __launch_bounds__(256)
void up2_v3(const float* __restrict__ x, const float* __restrict__ Wup,
            const float* __restrict__ bup, float* __restrict__ outp)
{
  const int gu   = __builtin_amdgcn_readfirstlane(threadIdx.x >> 6);
  const int lane = threadIdx.x & 63;
  const int k    = blockIdx.x & 7;
  const int n    = (blockIdx.x >> 3) * 64 + lane;

  float acc[16];
  #pragma unroll
  for (int i = 0; i < 16; ++i) acc[i] = 0.f;

  const float4* src = reinterpret_cast<const float4*>(x + (size_t)n * 64);
  const float* w = Wup + k * 4096 + gu * 16;
  #pragma unroll
  for (int c = 0; c < 4; ++c) {
    float4 a0 = src[c*4+0], a1 = src[c*4+1], a2 = src[c*4+2], a3 = src[c*4+3];
    float fr[16];
    fr[0]=a0.x; fr[1]=a0.y; fr[2]=a0.z; fr[3]=a0.w;
    fr[4]=a1.x; fr[5]=a1.y; fr[6]=a1.z; fr[7]=a1.w;
    fr[8]=a2.x; fr[9]=a2.y; fr[10]=a2.z; fr[11]=a2.w;
    fr[12]=a3.x; fr[13]=a3.y; fr[14]=a3.z; fr[15]=a3.w;
    #pragma unroll
    for (int u = 0; u < 16; ++u)
      #pragma unroll
      for (int j = 0; j < 16; ++j)
        acc[j] = fmaf(fr[u], w[(c * 16 + u) * 64 + j], acc[j]);
  }

  float* dst = outp + ((size_t)n * 8 + k) * 64 + gu * 16;
  #pragma unroll
  for (int q = 0; q < 4; ++q) {
    float4 o;
    float v0 = acc[4*q+0] + bup[gu*16 + 4*q+0]; o.x = v0 > 0.f ? v0 : 0.f;
    float v1 = acc[4*q+1] + bup[gu*16 + 4*q+1]; o.y = v1 > 0.f ? v1 : 0.f;
    float v2 = acc[4*q+2] + bup[gu*16 + 4*q+2]; o.z = v2 > 0.f ? v2 : 0.f;
    float v3 = acc[4*q+3] + bup[gu*16 + 4*q+3]; o.w = v3 > 0.f ? v3 : 0.f;
    reinterpret_cast<float4*>(dst)[q] = o;
  }
}

// ---------------------------------------------------------------------------
// cls pass 1: g[n][k] = feats[n] . Wcls[k]
// ---------------------------------------------------------------------------
__global__ __launch_bounds__(256)
void cls1_kernel(const float* __restrict__ feats, const float* __restrict__ Wcls,
                 float* __restrict__ g)
{
  const int n = blockIdx.x * 256 + threadIdx.x;
  if (blockIdx.x == 0 && threadIdx.x < 28) g[(size_t)NOUTC * 28 + threadIdx.x] = 0.f;
  const float4* src = reinterpret_cast<const float4*>(feats + (size_t)n * 64);
  float f[64];
  #pragma unroll
  for (int j = 0; j < 16; ++j) {
    float4 a = src[j];
    f[4*j+0]=a.x; f[4*j+1]=a.y; f[4*j+2]=a.z; f[4*j+3]=a.w;
  }
  #pragma unroll 1
  for (int k = 0; k < 27; ++k) {
    const float* w = Wcls + k * 64;
    float s0 = 0.f, s1 = 0.f, s2 = 0.f, s3 = 0.f;
    #pragma unroll
    for (int j = 0; j < 16; ++j) {
      s0 = fmaf(f[j],      w[j],      s0);
      s1 = fmaf(f[16 + j], w[16 + j], s1);
      s2 = fmaf(f[32 + j], w[32 + j], s2);
      s3 = fmaf(f[48 + j], w[48 + j], s3);
    }
    g[(size_t)n * 28 + k] = (s0 + s1) + (s2 + s3);
  }
}

__global__ __launch_bounds__(256)
void cls2_kernel(const float* __restrict__ g, const int* __restrict__ nbr,
                 const float* __restrict__ bcls, float* __restrict__ out_cls)
{
  const int n = blockIdx.x * 256 + threadIdx.x;
  float s = bcls[0];
  #pragma unroll 1
  for (int k = 0; k < 27; ++k) {
    int idx = nbr[(size_t)k * NOUTC + n];
    s += g[(size_t)idx * 28 + k];
  }
  out_cls[n] = s;
}

// ---------------------------------------------------------------------------
// init / detect / top-k select / prune
// ---------------------------------------------------------------------------
__global__ void init_kernel(uint* hist1, uint* hist2, int* tie_cnt, int* flag,
                            float* fa, float* fb, float* t0, float* t1)
{
  int i = blockIdx.x * 256 + threadIdx.x;
  if (i < 65536) hist1[i] = 0;
  else if (i < 131072) hist2[i - 65536] = 0;
  if (i == 0) { tie_cnt[0] = 0; flag[0] = 0; }
  if (i < 64) { fa[(size_t)NOUTC * 64 + i] = 0.f; fb[(size_t)NOUTC * 64 + i] = 0.f; }
  if (i < 16) { t0[(size_t)NOUTC * 16 + i] = 0.f; t1[(size_t)NOUTC * 16 + i] = 0.f; }
}

__global__ void detect_kernel(const unsigned char* __restrict__ mt, int* flag)
{
  int i = blockIdx.x * 256 + threadIdx.x;
  int p = i * 4 + 1;
  if (p < NOUTC && mt[p] != 0) flag[0] = 1;
}

__global__ void hist1_kernel(const float* __restrict__ cls, uint* __restrict__ hist)
{
  for (int i = blockIdx.x * blockDim.x + threadIdx.x; i < NOUTC; i += gridDim.x * blockDim.x)
    atomicAdd(&hist[fkey(cls[i]) >> 16], 1u);
}

__global__ void scan1_kernel(const uint* __restrict__ hist, const int* __restrict__ nums,
                             uint* __restrict__ res)
{
  __shared__ uint chunk[256];
  const int t = threadIdx.x;
  uint s = 0;
  for (int j = 0; j < 256; ++j) s += hist[t * 256 + j];
  chunk[t] = s;
  __syncthreads();
  if (t == 0) {
    uint k = (uint)nums[0];
    uint cum = 0; int c = 255;
    for (; c > 0; --c) { if (cum + chunk[c] >= k) break; cum += chunk[c]; }
    int B = c * 256; uint cum2 = cum;
    for (int b = c * 256 + 255; b >= c * 256; --b) {
      if (cum2 + hist[b] >= k) { B = b; break; }
      cum2 += hist[b];
    }
    res[0] = (uint)B; res[1] = cum2;
  }
}

__global__ void hist2_kernel(const float* __restrict__ cls, const uint* __restrict__ res1,
                             uint* __restrict__ hist)
{
  const uint B = res1[0];
  for (int i = blockIdx.x * blockDim.x + threadIdx.x; i < NOUTC; i += gridDim.x * blockDim.x) {
    uint key = fkey(cls[i]);
    if ((key >> 16) == B) atomicAdd(&hist[key & 0xffffu], 1u);
  }
}

__global__ void scan2_kernel(const uint* __restrict__ hist, const uint* __restrict__ res1,
                             const int* __restrict__ nums, uint* __restrict__ res2)
{
  __shared__ uint chunk[256];
  const int t = threadIdx.x;
  uint s = 0;
  for (int j = 0; j < 256; ++j) s += hist[t * 256 + j];
  chunk[t] = s;
  __syncthreads();
  if (t == 0) {
    uint k = (uint)nums[0];
    uint cum = res1[1]; int c = 255;
    for (; c > 0; --c) { if (cum + chunk[c] >= k) break; cum += chunk[c]; }
    int L = c * 256; uint cum2 = cum;
    for (int b = c * 256 + 255; b >= c * 256; --b) {
      if (cum2 + hist[b] >= k) { L = b; break; }
      cum2 += hist[b];
    }
    res2[0] = (res1[0] << 16) | (uint)L;
    res2[1] = k - cum2;
  }
}

__global__ void mark_kernel(const float* __restrict__ cls, const uint* __restrict__ res2,
                            unsigned char* __restrict__ msel, int* tie_cnt, int* tie_idx)
{
  const uint T = res2[0];
  for (int i = blockIdx.x * blockDim.x + threadIdx.x; i < NOUTC; i += gridDim.x * blockDim.x) {
    uint key = fkey(cls[i]);
    msel[i] = key > T ? 1 : 0;
    if (key == T) {
      int p = atomicAdd(tie_cnt, 1);
      if (p < 4096) tie_idx[p] = i;
    }
  }
}

__global__ void tie_kernel(const uint* __restrict__ res2, const int* __restrict__ tie_cnt,
                           const int* __restrict__ tie_idx, unsigned char* __restrict__ msel)
{
  int need = (int)res2[1];
  int cnt = tie_cnt[0]; if (cnt > 4096) cnt = 4096;
  if (need <= 0) return;
  if (cnt <= need) {
    for (int i = threadIdx.x; i < cnt; i += 256) msel[tie_idx[i]] = 1;
  } else {
    for (int i = threadIdx.x; i < cnt; i += 256) {
      int my = tie_idx[i];
      int rank = 0;
      for (int j = 0; j < cnt; ++j) rank += (tie_idx[j] < my) ? 1 : 0;
      if (rank < need) msel[my] = 1;
    }
  }
}

__global__ void prune_kernel(const float* __restrict__ feats, const unsigned char* __restrict__ msel,
                             const void* __restrict__ mtrue, const int* __restrict__ flag,
                             float* __restrict__ dout)
{
  const unsigned char* mb = (const unsigned char*)mtrue;
  const int* mi = (const int*)mtrue;
  const bool bytes = (flag[0] != 0);
  float* pruned = dout + NOUTC;
  float* maskf  = dout + NOUTC + (size_t)NOUTC * 64;
  const float4* src = reinterpret_cast<const float4*>(feats);
  float4* dst = reinterpret_cast<float4*>(pruned);
  const int total = NOUTC * 16;
  for (int i = blockIdx.x * blockDim.x + threadIdx.x; i < total; i += gridDim.x * blockDim.x) {
    int n = i >> 4;
    bool mt = bytes ? (mb[n] != 0) : (mi[n] != 0);
    bool m = (msel[n] != 0) || mt;
    float4 v = src[i];
    float4 z = {0.f, 0.f, 0.f, 0.f};
    dst[i] = m ? v : z;
    if ((i & 15) == 0) maskf[n] = m ? 1.f : 0.f;
  }
}

// ---------------------------------------------------------------------------
extern "C" void kernel_launch(void* const* d_in, const int* in_sizes, int n_in,
                              void* d_out, int out_size, void* d_ws, size_t ws_size,
                              hipStream_t stream)
{
  const float* x    = (const float*)d_in[0];
  const float* Wup  = (const float*)d_in[1];
  const float* bup  = (const float*)d_in[2];
  const float* Wc0  = (const float*)d_in[3];
  const float* bc0  = (const float*)d_in[4];
  const float* W00  = (const float*)d_in[5];
  const float* b00  = (const float*)d_in[6];
  const float* W01  = (const float*)d_in[7];
  const float* b01  = (const float*)d_in[8];
  const float* W10  = (const float*)d_in[9];
  const float* b10  = (const float*)d_in[10];
  const float* W11  = (const float*)d_in[11];
  const float* b11  = (const float*)d_in[12];
  const float* W12  = (const float*)d_in[13];
  const float* b12  = (const float*)d_in[14];
  const float* Wcls = (const float*)d_in[15];
  const float* bcls = (const float*)d_in[16];
  const int*   nbr  = (const int*)d_in[17];
  const void*  mtrue= d_in[18];
  const int*   nums = (const int*)d_in[19];

  float* dout = (float*)d_out;

  float* fa = (float*)d_ws;                       // (N+1)*64
  float* t0 = fa + (size_t)(NOUTC + 1) * 64;      // (N+1)*16
  float* t1 = t0 + (size_t)(NOUTC + 1) * 16;      // (N+1)*16
  float* g  = t0;                                 // (N+1)*28 overlay (dead by cls time)
  uint*  hist1 = (uint*)(t1 + (size_t)(NOUTC + 1) * 16);
  uint*  hist2 = hist1 + 65536;
  uint*  res1  = hist2 + 65536;
  uint*  res2  = res1 + 2;
  int*   tie_cnt = (int*)(res2 + 2);
  int*   flag    = tie_cnt + 1;
  int*   tie_idx = flag + 1;
  unsigned char* msel = (unsigned char*)(tie_idx + 4096);
  float* fb = dout + NOUTC;   // (N+1)*64 parked in d_out's pruned+mask region

  init_kernel<<<512, 256, 0, stream>>>(hist1, hist2, tie_cnt, flag, fa, fb, t0, t1);
  detect_kernel<<<128, 256, 0, stream>>>((const unsigned char*)mtrue, flag);

  up2_v3<<<2048, 256, 0, stream>>>(x, Wup, bup, fa);
  conv_c0_v4<<<2048, 256, 0, stream>>>(fa, nbr, Wc0, bc0, fb);

  const float* cur = fb; float* nxt = fa;
  for (int i = 0; i < 3; ++i) {
    conv_A_v4<<<2048, 256, 0, stream>>>(cur, nbr,
        W00 + (size_t)i * 27 * 1024, b00 + i * 16,
        W10 + (size_t)i * 1024,      b10 + i * 16, t0, t1);
    conv_B_v4<<<2048, 256, 0, stream>>>(t0, t1, cur, nbr,
        W01 + (size_t)i * 27 * 512, b01 + i * 32,
        W11 + (size_t)i * 27 * 256, b11 + i * 16,
        W12 + (size_t)i * 512,      b12 + i * 32, nxt);
    float* tmp = (float*)cur; cur = nxt; nxt = tmp;
  }
  // final features in fa

  cls1_kernel<<<512, 256, 0, stream>>>(cur, Wcls, g);
  cls2_kernel<<<512, 256, 0, stream>>>(g, nbr, bcls, dout);

  hist1_kernel<<<512, 256, 0, stream>>>(dout, hist1);
  scan1_kernel<<<1, 256, 0, stream>>>(hist1, nums, res1);
  hist2_kernel<<<512, 256, 0, stream>>>(dout, res1, hist2);
  scan2_kernel<<<1, 256, 0, stream>>>(hist2, res1, nums, res2);
  mark_kernel<<<512, 256, 0, stream>>>(dout, res2, msel, tie_cnt, tie_idx);
  tie_kernel<<<1, 256, 0, stream>>>(res2, tie_cnt, tie_idx, msel);
  prune_kernel<<<4096, 256, 0, stream>>>(cur, msel, mtrue, flag, dout);
}

// Round 7
// 1445.418 us; speedup vs baseline: 1.3540x; 1.3540x over previous
//
#include <hip/hip_runtime.h>
#include <cstdint>

#define NOUTC 131072
#define NINC  16384
#define CAP   204800        // sparse entry capacity (expected ~156K)
#define NCH   128           // chunks of 1024 rows
#define MAXB  3328          // phase1 grid (>= CAP/64)

using uint = unsigned int;

__device__ __forceinline__ uint fkey(float v){
  uint u = __float_as_uint(v);
  return (u & 0x80000000u) ? ~u : (u | 0x80000000u);
}

// tap index for output-child o gathering sibling q (d = q - o per dim)
__device__ __forceinline__ int ktap(int o, int q){
  int d0 = ((q>>2)&1) - ((o>>2)&1);
  int d1 = ((q>>1)&1) - ((o>>1)&1);
  int d2 = (q&1) - (o&1);
  return (d0+1)*9 + (d1+1)*3 + (d2+1);
}
// is tap k a guaranteed-sibling tap for child o?
__device__ __forceinline__ bool is_sib(int o, int k){
  int k0 = k/9, k1 = (k%9)/3, k2 = k%3;
  int q0 = ((o>>2)&1) + k0 - 1;
  int q1 = ((o>>1)&1) + k1 - 1;
  int q2 = (o&1)      + k2 - 1;
  return (q0>=0 && q0<=1 && q1>=0 && q1<=1 && q2>=0 && q2<=1);
}

// ---------------------------------------------------------------------------
// Sparse-entry list build: count -> scan -> fill (stable order => deterministic)
// ---------------------------------------------------------------------------
__global__ __launch_bounds__(256)
void count_kernel(const int* __restrict__ nbr, uint* __restrict__ counts)
{
  int k = blockIdx.x / NCH, cb = blockIdx.x % NCH;
  int t = threadIdx.x;
  int cnt = 0;
  for (int s = 0; s < 4; ++s){
    int row = cb*1024 + s*256 + t;
    int idx = nbr[(size_t)k*NOUTC + row];
    bool f = (idx != NOUTC) && !is_sib(row & 7, k);
    cnt += __syncthreads_count(f);
  }
  if (t == 0) counts[blockIdx.x] = (uint)cnt;
}

__global__ __launch_bounds__(256)
void scan_kernel(const uint* __restrict__ counts, uint* __restrict__ choff,
                 int* __restrict__ karr)
{
  __shared__ uint kt[27], segs[27], sege[27];
  int t = threadIdx.x;
  if (t < 27){ uint s = 0; for (int cb = 0; cb < NCH; ++cb) s += counts[t*NCH+cb]; kt[t] = s; }
  __syncthreads();
  if (t == 0){
    uint run = 0;
    for (int k = 0; k < 27; ++k){
      segs[k] = run;
      uint pad = (kt[k] + 63u) & ~63u;
      if (run + pad > CAP) pad = (run < CAP) ? ((CAP - run) & ~63u) : 0;
      run += pad;
      sege[k] = run;
    }
  }
  __syncthreads();
  if (t < 27){
    uint run = segs[t];
    for (int cb = 0; cb < NCH; ++cb){ choff[t*NCH+cb] = run; run += counts[t*NCH+cb]; }
  }
  __syncthreads();
  for (int b = t; b < MAXB; b += 256){
    int kk = -1; uint e = (uint)b * 64u;
    for (int k = 0; k < 27; ++k) if (e >= segs[k] && e < sege[k]) kk = k;
    karr[b] = kk;
  }
}

__global__ __launch_bounds__(256)
void fill_kernel(const int* __restrict__ nbr, const uint* __restrict__ choff,
                 uint2* __restrict__ entries)
{
  __shared__ uint wc[4][4];
  __shared__ uint sbase[4];
  int k = blockIdx.x / NCH, cb = blockIdx.x % NCH;
  int t = threadIdx.x, w = t >> 6, l = t & 63;
  uint base = choff[blockIdx.x];
  int rows[4], idxs[4];
  unsigned long long bal[4];
  for (int s = 0; s < 4; ++s){
    int row = cb*1024 + s*256 + t;
    int idx = nbr[(size_t)k*NOUTC + row];
    bool f = (idx != NOUTC) && !is_sib(row & 7, k);
    bal[s] = __ballot(f);
    if (l == 0) wc[s][w] = (uint)__popcll(bal[s]);
    rows[s] = row; idxs[s] = idx;
  }
  __syncthreads();
  if (t == 0){
    uint r = 0;
    for (int s = 0; s < 4; ++s){ sbase[s] = r; for (int w2 = 0; w2 < 4; ++w2) r += wc[s][w2]; }
  }
  __syncthreads();
  for (int s = 0; s < 4; ++s){
    if ((bal[s] >> l) & 1ull){
      uint off = sbase[s];
      for (int w2 = 0; w2 < w; ++w2) off += wc[s][w2];
      off += (uint)__popcll(bal[s] & ((1ull << l) - 1ull));
      uint pos = base + off;
      if (pos < CAP) entries[pos] = make_uint2((uint)rows[s], (uint)idxs[s]);
    }
  }
}

// ---------------------------------------------------------------------------
// c0 sibling kernel: out[8p+o] = bc0 + sum_{o'} f[8p+o'] @ Wc0[ktap(o,o')]
// block = 16 parents (128 rows), 256 thr (4 waves = ci-split), no gather.
// tiles: lane l -> (o = l>>3, pg = (l>>2)&1 [8 parents], cg = l&3 [16 couts])
// ---------------------------------------------------------------------------
__global__ __launch_bounds__(256)
void c0sib_kernel(const float* __restrict__ feats, const float* __restrict__ Wc0,
                  const float* __restrict__ bias, float* __restrict__ outp)
{
  __shared__ float smem[1280 + 14688];   // ft[8ci][8o'][20] + wb[8ci][27k][68]
  float* ft = smem;
  float* wb = smem + 1280;
  const int t = threadIdx.x, w = t >> 6, l = t & 63;
  const int o = l >> 3, pg = (l >> 2) & 1, cg = l & 3;
  const int base = blockIdx.x * 128;

  int kt8[8];
  #pragma unroll
  for (int q = 0; q < 8; ++q) kt8[q] = ktap(o, q);

  float acc[8][16];
  #pragma unroll
  for (int a = 0; a < 8; ++a)
    #pragma unroll
    for (int j = 0; j < 16; ++j) acc[a][j] = 0.f;

  for (int ch = 0; ch < 8; ++ch){
    { // stage features: 128 rows x 8 ci
      int row = base + (t >> 1), part = t & 1;
      float4 v = *reinterpret_cast<const float4*>(feats + (size_t)row*64 + ch*8 + part*4);
      int oo = row & 7, pp = (row >> 3) & 15;
      int cl = part * 4;
      ft[((cl+0)*8 + oo)*20 + pp] = v.x;
      ft[((cl+1)*8 + oo)*20 + pp] = v.y;
      ft[((cl+2)*8 + oo)*20 + pp] = v.z;
      ft[((cl+3)*8 + oo)*20 + pp] = v.w;
    }
    // stage weights: 27 taps x 8 ci x 64 co
    for (int e = t; e < 3456; e += 256){
      int c4 = e & 15, kk = (e >> 4) % 27, ci = (e >> 4) / 27;
      float4 v = *reinterpret_cast<const float4*>(Wc0 + (size_t)kk*4096 + (ch*8+ci)*64 + c4*4);
      *reinterpret_cast<float4*>(&wb[(ci*27 + kk)*68 + c4*4]) = v;
    }
    __syncthreads();
    #pragma unroll
    for (int ii = 0; ii < 2; ++ii){
      int ci = w * 2 + ii;
      #pragma unroll
      for (int q = 0; q < 8; ++q){
        const float* fp = &ft[(ci*8 + q)*20 + pg*8];
        float4 f0 = *reinterpret_cast<const float4*>(fp);
        float4 f1 = *reinterpret_cast<const float4*>(fp + 4);
        float fv[8] = {f0.x,f0.y,f0.z,f0.w, f1.x,f1.y,f1.z,f1.w};
        const float* wp = &wb[(ci*27 + kt8[q])*68 + cg*16];
        float4 w0 = *reinterpret_cast<const float4*>(wp);
        float4 w1 = *reinterpret_cast<const float4*>(wp + 4);
        float4 w2 = *reinterpret_cast<const float4*>(wp + 8);
        float4 w3 = *reinterpret_cast<const float4*>(wp + 12);
        float wv[16] = {w0.x,w0.y,w0.z,w0.w, w1.x,w1.y,w1.z,w1.w,
                        w2.x,w2.y,w2.z,w2.w, w3.x,w3.y,w3.z,w3.w};
        #pragma unroll
        for (int a = 0; a < 8; ++a)
          #pragma unroll
          for (int j = 0; j < 16; ++j)
            acc[a][j] = fmaf(fv[a], wv[j], acc[a][j]);
      }
    }
    __syncthreads();
  }

  // reduce across 4 ci-split waves (two cout-halves to bound LDS)
  float* red = wb;   // [128][68]
  #pragma unroll
  for (int hh = 0; hh < 2; ++hh){
    if (w >= 2){
      float* d = &red[((w-2)*64 + l)*68];
      #pragma unroll
      for (int a = 0; a < 8; ++a){
        float4 v0 = {acc[a][hh*8+0], acc[a][hh*8+1], acc[a][hh*8+2], acc[a][hh*8+3]};
        float4 v1 = {acc[a][hh*8+4], acc[a][hh*8+5], acc[a][hh*8+6], acc[a][hh*8+7]};
        *reinterpret_cast<float4*>(d + a*8)     = v0;
        *reinterpret_cast<float4*>(d + a*8 + 4) = v1;
      }
    }
    __syncthreads();
    if (w < 2){
      const float* s2 = &red[(w*64 + l)*68];
      #pragma unroll
      for (int a = 0; a < 8; ++a)
        #pragma unroll
        for (int j = 0; j < 8; ++j) acc[a][hh*8+j] += s2[a*8+j];
    }
    __syncthreads();
    if (w == 1){
      float* d = &red[l*68];
      #pragma unroll
      for (int a = 0; a < 8; ++a)
        #pragma unroll
        for (int j = 0; j < 8; ++j) d[a*8+j] = acc[a][hh*8+j];
    }
    __syncthreads();
    if (w == 0){
      const float* s2 = &red[l*68];
      #pragma unroll
      for (int a = 0; a < 8; ++a)
        #pragma unroll
        for (int j = 0; j < 8; ++j) acc[a][hh*8+j] += s2[a*8+j];
    }
    __syncthreads();
  }

  if (w == 0){
    #pragma unroll
    for (int pp = 0; pp < 8; ++pp){
      int row = base + (pg*8 + pp)*8 + o;
      float* dst = outp + (size_t)row*64 + cg*16;
      #pragma unroll
      for (int m = 0; m < 4; ++m){
        float4 v = {acc[pp][m*4+0] + bias[cg*16+m*4+0],
                    acc[pp][m*4+1] + bias[cg*16+m*4+1],
                    acc[pp][m*4+2] + bias[cg*16+m*4+2],
                    acc[pp][m*4+3] + bias[cg*16+m*4+3]};
        *reinterpret_cast<float4*>(dst + m*4) = v;   // no relu (sparse adds later)
      }
    }
  }
}

// ---------------------------------------------------------------------------
// A sibling kernel: t0[8p+o] = b00 + sum_{o'} f[8p+o'] @ W00[ktap(o,o')]
// block = 32 parents (256 rows); tiles: (o = l>>3, pg = l&7 [4 parents]), 16 couts
// ---------------------------------------------------------------------------
__global__ __launch_bounds__(256)
void asib_kernel(const float* __restrict__ feats, const float* __restrict__ W00i,
                 const float* __restrict__ b00i, float* __restrict__ t0)
{
  __shared__ float smem[8704];          // ft[8][8][36]=2304 + wb[8][27][20]=4320; red 128*68
  float* ft = smem;
  float* wb = smem + 2304;
  const int t = threadIdx.x, w = t >> 6, l = t & 63;
  const int o = l >> 3, pg = l & 7;
  const int base = blockIdx.x * 256;

  int kt8[8];
  #pragma unroll
  for (int q = 0; q < 8; ++q) kt8[q] = ktap(o, q);

  float acc[4][16];
  #pragma unroll
  for (int a = 0; a < 4; ++a)
    #pragma unroll
    for (int j = 0; j < 16; ++j) acc[a][j] = 0.f;

  for (int ch = 0; ch < 8; ++ch){
    { // stage features: 256 rows x 8 ci
      int row = base + t;
      float4 v0 = *reinterpret_cast<const float4*>(feats + (size_t)row*64 + ch*8);
      float4 v1 = *reinterpret_cast<const float4*>(feats + (size_t)row*64 + ch*8 + 4);
      int oo = row & 7, pp = (row >> 3) & 31;
      ft[((0)*8 + oo)*36 + pp] = v0.x; ft[((1)*8 + oo)*36 + pp] = v0.y;
      ft[((2)*8 + oo)*36 + pp] = v0.z; ft[((3)*8 + oo)*36 + pp] = v0.w;
      ft[((4)*8 + oo)*36 + pp] = v1.x; ft[((5)*8 + oo)*36 + pp] = v1.y;
      ft[((6)*8 + oo)*36 + pp] = v1.z; ft[((7)*8 + oo)*36 + pp] = v1.w;
    }
    for (int e = t; e < 864; e += 256){
      int c4 = e & 3, kk = (e >> 2) % 27, ci = (e >> 2) / 27;
      float4 v = *reinterpret_cast<const float4*>(W00i + (size_t)kk*1024 + (ch*8+ci)*16 + c4*4);
      *reinterpret_cast<float4*>(&wb[(ci*27 + kk)*20 + c4*4]) = v;
    }
    __syncthreads();
    #pragma unroll
    for (int ii = 0; ii < 2; ++ii){
      int ci = w * 2 + ii;
      #pragma unroll
      for (int q = 0; q < 8; ++q){
        float4 f0 = *reinterpret_cast<const float4*>(&ft[(ci*8 + q)*36 + pg*4]);
        float fv[4] = {f0.x, f0.y, f0.z, f0.w};
        const float* wp = &wb[(ci*27 + kt8[q])*20];
        float4 w0 = *reinterpret_cast<const float4*>(wp);
        float4 w1 = *reinterpret_cast<const float4*>(wp + 4);
        float4 w2 = *reinterpret_cast<const float4*>(wp + 8);
        float4 w3 = *reinterpret_cast<const float4*>(wp + 12);
        float wv[16] = {w0.x,w0.y,w0.z,w0.w, w1.x,w1.y,w1.z,w1.w,
                        w2.x,w2.y,w2.z,w2.w, w3.x,w3.y,w3.z,w3.w};
        #pragma unroll
        for (int a = 0; a < 4; ++a)
          #pragma unroll
          for (int j = 0; j < 16; ++j)
            acc[a][j] = fmaf(fv[a], wv[j], acc[a][j]);
      }
    }
    __syncthreads();
  }

  float* red = smem;     // [128][68]
  if (w >= 2){
    float* d = &red[((w-2)*64 + l)*68];
    #pragma unroll
    for (int a = 0; a < 4; ++a){
      #pragma unroll
      for (int m = 0; m < 4; ++m){
        float4 v = {acc[a][m*4+0], acc[a][m*4+1], acc[a][m*4+2], acc[a][m*4+3]};
        *reinterpret_cast<float4*>(d + a*16 + m*4) = v;
      }
    }
  }
  __syncthreads();
  if (w < 2){
    const float* s2 = &red[(w*64 + l)*68];
    #pragma unroll
    for (int a = 0; a < 4; ++a)
      #pragma unroll
      for (int j = 0; j < 16; ++j) acc[a][j] += s2[a*16+j];
  }
  __syncthreads();
  if (w == 1){
    float* d = &red[l*68];
    #pragma unroll
    for (int a = 0; a < 4; ++a)
      #pragma unroll
      for (int j = 0; j < 16; ++j) d[a*16+j] = acc[a][j];
  }
  __syncthreads();
  if (w == 0){
    const float* s2 = &red[l*68];
    #pragma unroll
    for (int a = 0; a < 4; ++a)
      #pragma unroll
      for (int j = 0; j < 16; ++j) acc[a][j] += s2[a*16+j];
    #pragma unroll
    for (int pp = 0; pp < 4; ++pp){
      int row = base + (pg*4 + pp)*8 + o;
      float* dst = t0 + (size_t)row*16;
      #pragma unroll
      for (int m = 0; m < 4; ++m){
        float4 v = {acc[pp][m*4+0] + b00i[m*4+0], acc[pp][m*4+1] + b00i[m*4+1],
                    acc[pp][m*4+2] + b00i[m*4+2], acc[pp][m*4+3] + b00i[m*4+3]};
        *reinterpret_cast<float4*>(dst + m*4) = v;  // no relu yet
      }
    }
  }
}

// ---------------------------------------------------------------------------
// Sparse phase1: 64 entries/block dense GEMM into slab (global slot = b*64+e)
// ---------------------------------------------------------------------------
__global__ __launch_bounds__(128)
void p1c0_kernel(const float* __restrict__ feats, const float* __restrict__ Wc0,
                 const uint2* __restrict__ entries, const int* __restrict__ karr,
                 float* __restrict__ slab, int h)
{
  __shared__ float ft2[64*68];
  __shared__ float wbs[64*36];
  int b = blockIdx.x;
  int k = karr[b];
  if (k < 0) return;
  int t = threadIdx.x;
  for (int e = t; e < 512; e += 128){
    int ci = e >> 3, c4 = e & 7;
    float4 v = *reinterpret_cast<const float4*>(Wc0 + (size_t)k*4096 + ci*64 + h*32 + c4*4);
    *reinterpret_cast<float4*>(&wbs[ci*36 + c4*4]) = v;
  }
  {
    int e = t >> 1, part = t & 1;
    uint2 en = entries[(size_t)b*64 + e];
    int gidx = (en.x == 0xFFFFFFFFu) ? NOUTC : (int)en.y;
    const float4* src = reinterpret_cast<const float4*>(feats + (size_t)gidx*64 + part*32);
    #pragma unroll
    for (int j = 0; j < 8; ++j){
      float4 v = src[j];
      int ci = part*32 + j*4;
      ft2[(ci+0)*68 + e] = v.x; ft2[(ci+1)*68 + e] = v.y;
      ft2[(ci+2)*68 + e] = v.z; ft2[(ci+3)*68 + e] = v.w;
    }
  }
  __syncthreads();
  int sp = t & 1, tile = t >> 1, eg = tile >> 3, cg = tile & 7;
  float acc[8][4];
  #pragma unroll
  for (int a = 0; a < 8; ++a){ acc[a][0]=0.f; acc[a][1]=0.f; acc[a][2]=0.f; acc[a][3]=0.f; }
  for (int i = 0; i < 32; ++i){
    int ci = sp + 2*i;
    float4 f0 = *reinterpret_cast<const float4*>(&ft2[ci*68 + eg*8]);
    float4 f1 = *reinterpret_cast<const float4*>(&ft2[ci*68 + eg*8 + 4]);
    float fv[8] = {f0.x,f0.y,f0.z,f0.w, f1.x,f1.y,f1.z,f1.w};
    float4 wv = *reinterpret_cast<const float4*>(&wbs[ci*36 + cg*4]);
    float wa[4] = {wv.x, wv.y, wv.z, wv.w};
    #pragma unroll
    for (int a = 0; a < 8; ++a)
      #pragma unroll
      for (int j = 0; j < 4; ++j)
        acc[a][j] = fmaf(fv[a], wa[j], acc[a][j]);
  }
  #pragma unroll
  for (int a = 0; a < 8; ++a)
    #pragma unroll
    for (int j = 0; j < 4; ++j) acc[a][j] += __shfl_xor(acc[a][j], 1, 64);
  if (sp == 0){
    #pragma unroll
    for (int a = 0; a < 8; ++a){
      int e = eg*8 + a;
      float4 v = {acc[a][0], acc[a][1], acc[a][2], acc[a][3]};
      *reinterpret_cast<float4*>(&slab[((size_t)b*64 + e)*32 + cg*4]) = v;
    }
  }
}

__global__ __launch_bounds__(128)
void p1a_kernel(const float* __restrict__ feats, const float* __restrict__ W00i,
                const uint2* __restrict__ entries, const int* __restrict__ karr,
                float* __restrict__ slab)
{
  __shared__ float ft2[64*68];
  __shared__ float wbs[64*18];
  int b = blockIdx.x;
  int k = karr[b];
  if (k < 0) return;
  int t = threadIdx.x;
  for (int e = t; e < 256; e += 128){
    int ci = e >> 2, c4 = e & 3;
    float4 v = *reinterpret_cast<const float4*>(W00i + (size_t)k*1024 + ci*16 + c4*4);
    *reinterpret_cast<float4*>(&wbs[ci*18 + c4*4]) = v;
  }
  {
    int e = t >> 1, part = t & 1;
    uint2 en = entries[(size_t)b*64 + e];
    int gidx = (en.x == 0xFFFFFFFFu) ? NOUTC : (int)en.y;
    const float4* src = reinterpret_cast<const float4*>(feats + (size_t)gidx*64 + part*32);
    #pragma unroll
    for (int j = 0; j < 8; ++j){
      float4 v = src[j];
      int ci = part*32 + j*4;
      ft2[(ci+0)*68 + e] = v.x; ft2[(ci+1)*68 + e] = v.y;
      ft2[(ci+2)*68 + e] = v.z; ft2[(ci+3)*68 + e] = v.w;
    }
  }
  __syncthreads();
  int sp = t & 1, tile = t >> 1, eg = tile >> 2, cg = tile & 3;
  float acc[4][4];
  #pragma unroll
  for (int a = 0; a < 4; ++a){ acc[a][0]=0.f; acc[a][1]=0.f; acc[a][2]=0.f; acc[a][3]=0.f; }
  for (int i = 0; i < 32; ++i){
    int ci = sp + 2*i;
    float4 f0 = *reinterpret_cast<const float4*>(&ft2[ci*68 + eg*4]);
    float fv[4] = {f0.x, f0.y, f0.z, f0.w};
    float4 wv = *reinterpret_cast<const float4*>(&wbs[ci*18 + cg*4]);
    float wa[4] = {wv.x, wv.y, wv.z, wv.w};
    #pragma unroll
    for (int a = 0; a < 4; ++a)
      #pragma unroll
      for (int j = 0; j < 4; ++j)
        acc[a][j] = fmaf(fv[a], wa[j], acc[a][j]);
  }
  #pragma unroll
  for (int a = 0; a < 4; ++a)
    #pragma unroll
    for (int j = 0; j < 4; ++j) acc[a][j] += __shfl_xor(acc[a][j], 1, 64);
  if (sp == 0){
    #pragma unroll
    for (int a = 0; a < 4; ++a){
      int e = eg*4 + a;
      float4 v = {acc[a][0], acc[a][1], acc[a][2], acc[a][3]};
      *reinterpret_cast<float4*>(&slab[((size_t)b*64 + e)*16 + cg*4]) = v;
    }
  }
}

// ---------------------------------------------------------------------------
// Combine: per-row exclusive; recomputes fill's stable ranks; adds slab; relu.
// ---------------------------------------------------------------------------
__global__ __launch_bounds__(256)
void cmbc0_kernel(const int* __restrict__ nbr, const uint* __restrict__ choff,
                  const float* __restrict__ slab, float* __restrict__ fb, int h)
{
  __shared__ uint wc[4][4];
  int cb = blockIdx.x >> 1, cq = blockIdx.x & 1;
  int t = threadIdx.x, w = t >> 6, l = t & 63;
  int co0 = h*32 + cq*16;
  float acc[4][16];
  #pragma unroll
  for (int s = 0; s < 4; ++s)
    #pragma unroll
    for (int j = 0; j < 16; ++j) acc[s][j] = 0.f;

  for (int k = 0; k < 27; ++k){
    unsigned long long bal[4];
    for (int s = 0; s < 4; ++s){
      int row = cb*1024 + s*256 + t;
      int idx = nbr[(size_t)k*NOUTC + row];
      bool f = (idx != NOUTC) && !is_sib(row & 7, k);
      bal[s] = __ballot(f);
      if (l == 0) wc[s][w] = (uint)__popcll(bal[s]);
    }
    __syncthreads();
    uint sbs[4];
    { uint r = 0; for (int s = 0; s < 4; ++s){ sbs[s] = r; for (int w2 = 0; w2 < 4; ++w2) r += wc[s][w2]; } }
    uint base = choff[k*NCH + cb];
    for (int s = 0; s < 4; ++s){
      if ((bal[s] >> l) & 1ull){
        uint off = sbs[s];
        for (int w2 = 0; w2 < w; ++w2) off += wc[s][w2];
        off += (uint)__popcll(bal[s] & ((1ull << l) - 1ull));
        uint pos = base + off;
        if (pos < CAP){
          const float4* sr = reinterpret_cast<const float4*>(slab + (size_t)pos*32 + cq*16);
          float4 a0 = sr[0], a1 = sr[1], a2 = sr[2], a3 = sr[3];
          acc[s][0]+=a0.x; acc[s][1]+=a0.y; acc[s][2]+=a0.z; acc[s][3]+=a0.w;
          acc[s][4]+=a1.x; acc[s][5]+=a1.y; acc[s][6]+=a1.z; acc[s][7]+=a1.w;
          acc[s][8]+=a2.x; acc[s][9]+=a2.y; acc[s][10]+=a2.z; acc[s][11]+=a2.w;
          acc[s][12]+=a3.x; acc[s][13]+=a3.y; acc[s][14]+=a3.z; acc[s][15]+=a3.w;
        }
      }
    }
    __syncthreads();
  }
  for (int s = 0; s < 4; ++s){
    int row = cb*1024 + s*256 + t;
    float* dst = fb + (size_t)row*64 + co0;
    #pragma unroll
    for (int m = 0; m < 4; ++m){
      float4 b0 = *reinterpret_cast<const float4*>(dst + m*4);
      float4 v;
      v.x = b0.x + acc[s][m*4+0]; v.x = v.x > 0.f ? v.x : 0.f;
      v.y = b0.y + acc[s][m*4+1]; v.y = v.y > 0.f ? v.y : 0.f;
      v.z = b0.z + acc[s][m*4+2]; v.z = v.z > 0.f ? v.z : 0.f;
      v.w = b0.w + acc[s][m*4+3]; v.w = v.w > 0.f ? v.w : 0.f;
      *reinterpret_cast<float4*>(dst + m*4) = v;
    }
  }
}

__global__ __launch_bounds__(256)
void cmba_kernel(const int* __restrict__ nbr, const uint* __restrict__ choff,
                 const float* __restrict__ slab, float* __restrict__ t0)
{
  __shared__ uint wc[4][4];
  int cb = blockIdx.x;
  int t = threadIdx.x, w = t >> 6, l = t & 63;
  float acc[4][16];
  #pragma unroll
  for (int s = 0; s < 4; ++s)
    #pragma unroll
    for (int j = 0; j < 16; ++j) acc[s][j] = 0.f;

  for (int k = 0; k < 27; ++k){
    unsigned long long bal[4];
    for (int s = 0; s < 4; ++s){
      int row = cb*1024 + s*256 + t;
      int idx = nbr[(size_t)k*NOUTC + row];
      bool f = (idx != NOUTC) && !is_sib(row & 7, k);
      bal[s] = __ballot(f);
      if (l == 0) wc[s][w] = (uint)__popcll(bal[s]);
    }
    __syncthreads();
    uint sbs[4];
    { uint r = 0; for (int s = 0; s < 4; ++s){ sbs[s] = r; for (int w2 = 0; w2 < 4; ++w2) r += wc[s][w2]; } }
    uint base = choff[k*NCH + cb];
    for (int s = 0; s < 4; ++s){
      if ((bal[s] >> l) & 1ull){
        uint off = sbs[s];
        for (int w2 = 0; w2 < w; ++w2) off += wc[s][w2];
        off += (uint)__popcll(bal[s] & ((1ull << l) - 1ull));
        uint pos = base + off;
        if (pos < CAP){
          const float4* sr = reinterpret_cast<const float4*>(slab + (size_t)pos*16);
          float4 a0 = sr[0], a1 = sr[1], a2 = sr[2], a3 = sr[3];
          acc[s][0]+=a0.x; acc[s][1]+=a0.y; acc[s][2]+=a0.z; acc[s][3]+=a0.w;
          acc[s][4]+=a1.x; acc[s][5]+=a1.y; acc[s][6]+=a1.z; acc[s][7]+=a1.w;
          acc[s][8]+=a2.x; acc[s][9]+=a2.y; acc[s][10]+=a2.z; acc[s][11]+=a2.w;
          acc[s][12]+=a3.x; acc[s][13]+=a3.y; acc[s][14]+=a3.z; acc[s][15]+=a3.w;
        }
      }
    }
    __syncthreads();
  }
  for (int s = 0; s < 4; ++s){
    int row = cb*1024 + s*256 + t;
    float* dst = t0 + (size_t)row*16;
    #pragma unroll
    for (int m = 0; m < 4; ++m){
      float4 b0 = *reinterpret_cast<const float4*>(dst + m*4);
      float4 v;
      v.x = b0.x + acc[s][m*4+0]; v.x = v.x > 0.f ? v.x : 0.f;
      v.y = b0.y + acc[s][m*4+1]; v.y = v.y > 0.f ? v.y : 0.f;
      v.z = b0.z + acc[s][m*4+2]; v.z = v.z > 0.f ? v.z : 0.f;
      v.w = b0.w + acc[s][m*4+3]; v.w = v.w > 0.f ? v.w : 0.f;
      *reinterpret_cast<float4*>(dst + m*4) = v;
    }
  }
}

// ---------------------------------------------------------------------------
// R2-proven spconv2 (used for W10, W01, W11, W12)
// ---------------------------------------------------------------------------
template<int ROWS, int CIN, int COUT, int SPLIT, int THREADS, int NK,
         bool IDENT, bool RELU, bool RESID>
__global__ __launch_bounds__(THREADS)
void spconv2(const float* __restrict__ feats, const int* __restrict__ nbr,
             const float* __restrict__ Wg, const float* __restrict__ bias,
             const float* __restrict__ resid, float* __restrict__ outp,
             int ostride, int coff)
{
  constexpr int RG = ROWS / 8, CG = COUT / 8;
  static_assert(RG * CG * SPLIT == THREADS, "bad thread tiling");
  constexpr int CIPT = CIN / SPLIT;
  constexpr int STR  = ROWS + 4;
  constexpr int WSTR = COUT + 4;
  constexpr int TPR  = THREADS / ROWS;
  constexpr int FSTG = CIN / TPR;
  constexpr int WSTG = (CIN * COUT) / THREADS;
  constexpr int NSLOT = THREADS / SPLIT;

  constexpr int MAIN_FL = CIN * STR + CIN * WSTR;
  constexpr int RED_FL  = (SPLIT > 1) ? (THREADS / 2) * 64 : 0;
  constexpr int LDS_FL  = MAIN_FL > RED_FL ? MAIN_FL : RED_FL;
  __shared__ float smem[LDS_FL];
  float* ft = smem;
  float* Wl = smem + CIN * STR;

  const int t    = threadIdx.x;
  const int base = blockIdx.x * ROWS;
  const int sp   = t % SPLIT;
  const int slot = t / SPLIT;
  const int rg = slot / CG, cg = slot % CG;
  const int trr = rg * 8, tcc = cg * 8;
  const int gr = t / TPR, part = t % TPR;

  float4 fstg[FSTG / 4];
  alignas(16) float wstg[WSTG];
  float acc[8][8];
  #pragma unroll
  for (int a = 0; a < 8; ++a)
    #pragma unroll
    for (int b = 0; b < 8; ++b) acc[a][b] = 0.f;

  auto load_f = [&](int k) {
    int gidx = IDENT ? (base + gr) : nbr[(size_t)k * NOUTC + base + gr];
    const float4* src = reinterpret_cast<const float4*>(feats + (size_t)gidx * CIN + part * FSTG);
    #pragma unroll
    for (int j = 0; j < FSTG / 4; ++j) fstg[j] = src[j];
  };
  auto load_w = [&](int k) {
    const float* wsrc = Wg + (size_t)k * CIN * COUT + t * WSTG;
    if constexpr (WSTG % 4 == 0) {
      #pragma unroll
      for (int m = 0; m < WSTG / 4; ++m)
        *reinterpret_cast<float4*>(&wstg[4 * m]) = reinterpret_cast<const float4*>(wsrc)[m];
    } else {
      *reinterpret_cast<float2*>(&wstg[0]) = *reinterpret_cast<const float2*>(wsrc);
    }
  };

  load_f(0); load_w(0);

  for (int k = 0; k < NK; ++k) {
    #pragma unroll
    for (int j = 0; j < FSTG / 4; ++j) {
      int ci = part * FSTG + 4 * j;
      ft[(ci + 0) * STR + gr] = fstg[j].x;
      ft[(ci + 1) * STR + gr] = fstg[j].y;
      ft[(ci + 2) * STR + gr] = fstg[j].z;
      ft[(ci + 3) * STR + gr] = fstg[j].w;
    }
    #pragma unroll
    for (int m = 0; m < WSTG; ++m) {
      int widx = t * WSTG + m;
      Wl[(widx / COUT) * WSTR + (widx % COUT)] = wstg[m];
    }
    __syncthreads();
    if (k + 1 < NK) { load_f(k + 1); load_w(k + 1); }
    #pragma unroll 4
    for (int i = 0; i < CIPT; ++i) {
      int ci = sp + SPLIT * i;
      float4 f0 = *reinterpret_cast<const float4*>(&ft[ci * STR + trr]);
      float4 f1 = *reinterpret_cast<const float4*>(&ft[ci * STR + trr + 4]);
      float4 w0 = *reinterpret_cast<const float4*>(&Wl[ci * WSTR + tcc]);
      float4 w1 = *reinterpret_cast<const float4*>(&Wl[ci * WSTR + tcc + 4]);
      float fv[8] = {f0.x, f0.y, f0.z, f0.w, f1.x, f1.y, f1.z, f1.w};
      float wv[8] = {w0.x, w0.y, w0.z, w0.w, w1.x, w1.y, w1.z, w1.w};
      #pragma unroll
      for (int a = 0; a < 8; ++a)
        #pragma unroll
        for (int b = 0; b < 8; ++b)
          acc[a][b] = fmaf(fv[a], wv[b], acc[a][b]);
    }
    __syncthreads();
  }

  if constexpr (SPLIT > 1) {
    float* red = smem;
    for (int off = SPLIT / 2; off >= 1; off >>= 1) {
      __syncthreads();
      if (sp >= off && sp < 2 * off) {
        float* dst = red + ((size_t)((sp - off) * NSLOT + slot)) * 64;
        #pragma unroll
        for (int a = 0; a < 8; ++a) {
          float4 v0 = {acc[a][0], acc[a][1], acc[a][2], acc[a][3]};
          float4 v1 = {acc[a][4], acc[a][5], acc[a][6], acc[a][7]};
          *reinterpret_cast<float4*>(dst + a * 8)     = v0;
          *reinterpret_cast<float4*>(dst + a * 8 + 4) = v1;
        }
      }
      __syncthreads();
      if (sp < off) {
        const float* s = red + ((size_t)(sp * NSLOT + slot)) * 64;
        #pragma unroll
        for (int a = 0; a < 8; ++a) {
          float4 v0 = *reinterpret_cast<const float4*>(s + a * 8);
          float4 v1 = *reinterpret_cast<const float4*>(s + a * 8 + 4);
          acc[a][0] += v0.x; acc[a][1] += v0.y; acc[a][2] += v0.z; acc[a][3] += v0.w;
          acc[a][4] += v1.x; acc[a][5] += v1.y; acc[a][6] += v1.z; acc[a][7] += v1.w;
        }
      }
    }
  }

  if (sp == 0) {
    #pragma unroll
    for (int a = 0; a < 8; ++a) {
      int r = base + trr + a;
      float o[8];
      #pragma unroll
      for (int b = 0; b < 8; ++b) {
        float v = acc[a][b] + bias[tcc + b];
        if (RELU) v = v > 0.f ? v : 0.f;
        o[b] = v;
      }
      if (RESID) {
        const float* rs = resid + (size_t)r * 64 + coff + tcc;
        float4 r0 = *reinterpret_cast<const float4*>(rs);
        float4 r1 = *reinterpret_cast<const float4*>(rs + 4);
        o[0] += r0.x; o[1] += r0.y; o[2] += r0.z; o[3] += r0.w;
        o[4] += r1.x; o[5] += r1.y; o[6] += r1.z; o[7] += r1.w;
      }
      float* dst = outp + (size_t)r * ostride + coff + tcc;
      float4 s0 = {o[0], o[1], o[2], o[3]};
      float4 s1 = {o[4], o[5], o[6], o[7]};
      *reinterpret_cast<float4*>(dst)     = s0;
      *reinterpret_cast<float4*>(dst + 4) = s1;
    }
  }
}

// ---------------------------------------------------------------------------
// upsample (R2)
// ---------------------------------------------------------------------------
__global__ __launch_bounds__(256)
void upsample_kernel(const float* __restrict__ x, const float* __restrict__ Wup,
                     const float* __restrict__ bup, float* __restrict__ outp)
{
  __shared__ float Wl[64 * 64];
  __shared__ float xt[64][68];
  const int t    = threadIdx.x;
  const int tile = blockIdx.x >> 3;
  const int k    = blockIdx.x & 7;
  const int base = tile * 64;

  #pragma unroll
  for (int i = t; i < 4096; i += 256) Wl[i] = Wup[k * 4096 + i];
  {
    const int gr = t >> 2, gp = t & 3;
    const float4* src = reinterpret_cast<const float4*>(x + (size_t)(base + gr) * 64) + gp * 4;
    #pragma unroll
    for (int j = 0; j < 4; ++j) {
      float4 v = src[j];
      int ci = (gp * 4 + j) * 4;
      xt[ci + 0][gr] = v.x; xt[ci + 1][gr] = v.y;
      xt[ci + 2][gr] = v.z; xt[ci + 3][gr] = v.w;
    }
  }
  __syncthreads();
  const int tcc = (t % 16) * 4, trr = (t / 16) * 4;
  float acc[4][4];
  #pragma unroll
  for (int a = 0; a < 4; ++a)
    #pragma unroll
    for (int b = 0; b < 4; ++b) acc[a][b] = 0.f;
  #pragma unroll
  for (int ci = 0; ci < 64; ++ci) {
    float4 f = *reinterpret_cast<const float4*>(&xt[ci][trr]);
    float4 w = *reinterpret_cast<const float4*>(&Wl[ci * 64 + tcc]);
    float fv[4] = {f.x, f.y, f.z, f.w};
    float wv[4] = {w.x, w.y, w.z, w.w};
    #pragma unroll
    for (int a = 0; a < 4; ++a)
      #pragma unroll
      for (int b = 0; b < 4; ++b) acc[a][b] = fmaf(fv[a], wv[b], acc[a][b]);
  }
  #pragma unroll
  for (int a = 0; a < 4; ++a) {
    int n = base + trr + a;
    float4 o;
    float v0 = acc[a][0] + bup[tcc + 0]; o.x = v0 > 0.f ? v0 : 0.f;
    float v1 = acc[a][1] + bup[tcc + 1]; o.y = v1 > 0.f ? v1 : 0.f;
    float v2 = acc[a][2] + bup[tcc + 2]; o.z = v2 > 0.f ? v2 : 0.f;
    float v3 = acc[a][3] + bup[tcc + 3]; o.w = v3 > 0.f ? v3 : 0.f;
    *reinterpret_cast<float4*>(outp + ((size_t)n * 8 + k) * 64 + tcc) = o;
  }
}

// ---------------------------------------------------------------------------
// cls / init / detect / topk / prune (unchanged)
// ---------------------------------------------------------------------------
__global__ __launch_bounds__(256)
void cls1_kernel(const float* __restrict__ feats, const float* __restrict__ Wcls,
                 float* __restrict__ g)
{
  const int n = blockIdx.x * 256 + threadIdx.x;
  if (blockIdx.x == 0 && threadIdx.x < 28) g[(size_t)NOUTC * 28 + threadIdx.x] = 0.f;
  const float4* src = reinterpret_cast<const float4*>(feats + (size_t)n * 64);
  float f[64];
  #pragma unroll
  for (int j = 0; j < 16; ++j) {
    float4 a = src[j];
    f[4*j+0]=a.x; f[4*j+1]=a.y; f[4*j+2]=a.z; f[4*j+3]=a.w;
  }
  #pragma unroll 1
  for (int k = 0; k < 27; ++k) {
    const float* w = Wcls + k * 64;
    float s0 = 0.f, s1 = 0.f, s2 = 0.f, s3 = 0.f;
    #pragma unroll
    for (int j = 0; j < 16; ++j) {
      s0 = fmaf(f[j],      w[j],      s0);
      s1 = fmaf(f[16 + j], w[16 + j], s1);
      s2 = fmaf(f[32 + j], w[32 + j], s2);
      s3 = fmaf(f[48 + j], w[48 + j], s3);
    }
    g[(size_t)n * 28 + k] = (s0 + s1) + (s2 + s3);
  }
}

__global__ __launch_bounds__(256)
void cls2_kernel(const float* __restrict__ g, const int* __restrict__ nbr,
                 const float* __restrict__ bcls, float* __restrict__ out_cls)
{
  const int n = blockIdx.x * 256 + threadIdx.x;
  float s = bcls[0];
  #pragma unroll 1
  for (int k = 0; k < 27; ++k) {
    int idx = nbr[(size_t)k * NOUTC + n];
    s += g[(size_t)idx * 28 + k];
  }
  out_cls[n] = s;
}

__global__ void init_kernel(uint* hist1, uint* hist2, int* tie_cnt, int* flag,
                            float* fa, float* fb, float* t0, float* t1)
{
  int i = blockIdx.x * 256 + threadIdx.x;
  if (i < 65536) hist1[i] = 0;
  else if (i < 131072) hist2[i - 65536] = 0;
  if (i == 0) { tie_cnt[0] = 0; flag[0] = 0; }
  if (i < 64) { fa[(size_t)NOUTC * 64 + i] = 0.f; fb[(size_t)NOUTC * 64 + i] = 0.f; }
  if (i < 16) { t0[(size_t)NOUTC * 16 + i] = 0.f; t1[(size_t)NOUTC * 16 + i] = 0.f; }
}

__global__ void detect_kernel(const unsigned char* __restrict__ mt, int* flag)
{
  int i = blockIdx.x * 256 + threadIdx.x;
  int p = i * 4 + 1;
  if (p < NOUTC && mt[p] != 0) flag[0] = 1;
}

__global__ void hist1_kernel(const float* __restrict__ cls, uint* __restrict__ hist)
{
  for (int i = blockIdx.x * blockDim.x + threadIdx.x; i < NOUTC; i += gridDim.x * blockDim.x)
    atomicAdd(&hist[fkey(cls[i]) >> 16], 1u);
}

__global__ void scan1_kernel(const uint* __restrict__ hist, const int* __restrict__ nums,
                             uint* __restrict__ res)
{
  __shared__ uint chunk[256];
  const int t = threadIdx.x;
  uint s = 0;
  for (int j = 0; j < 256; ++j) s += hist[t * 256 + j];
  chunk[t] = s;
  __syncthreads();
  if (t == 0) {
    uint k = (uint)nums[0];
    uint cum = 0; int c = 255;
    for (; c > 0; --c) { if (cum + chunk[c] >= k) break; cum += chunk[c]; }
    int B = c * 256; uint cum2 = cum;
    for (int b = c * 256 + 255; b >= c * 256; --b) {
      if (cum2 + hist[b] >= k) { B = b; break; }
      cum2 += hist[b];
    }
    res[0] = (uint)B; res[1] = cum2;
  }
}

__global__ void hist2_kernel(const float* __restrict__ cls, const uint* __restrict__ res1,
                             uint* __restrict__ hist)
{
  const uint B = res1[0];
  for (int i = blockIdx.x * blockDim.x + threadIdx.x; i < NOUTC; i += gridDim.x * blockDim.x) {
    uint key = fkey(cls[i]);
    if ((key >> 16) == B) atomicAdd(&hist[key & 0xffffu], 1u);
  }
}

__global__ void scan2_kernel(const uint* __restrict__ hist, const uint* __restrict__ res1,
                             const int* __restrict__ nums, uint* __restrict__ res2)
{
  __shared__ uint chunk[256];
  const int t = threadIdx.x;
  uint s = 0;
  for (int j = 0; j < 256; ++j) s += hist[t * 256 + j];
  chunk[t] = s;
  __syncthreads();
  if (t == 0) {
    uint k = (uint)nums[0];
    uint cum = res1[1]; int c = 255;
    for (; c > 0; --c) { if (cum + chunk[c] >= k) break; cum += chunk[c]; }
    int L = c * 256; uint cum2 = cum;
    for (int b = c * 256 + 255; b >= c * 256; --b) {
      if (cum2 + hist[b] >= k) { L = b; break; }
      cum2 += hist[b];
    }
    res2[0] = (res1[0] << 16) | (uint)L;
    res2[1] = k - cum2;
  }
}

__global__ void mark_kernel(const float* __restrict__ cls, const uint* __restrict__ res2,
                            unsigned char* __restrict__ msel, int* tie_cnt, int* tie_idx)
{
  const uint T = res2[0];
  for (int i = blockIdx.x * blockDim.x + threadIdx.x; i < NOUTC; i += gridDim.x * blockDim.x) {
    uint key = fkey(cls[i]);
    msel[i] = key > T ? 1 : 0;
    if (key == T) {
      int p = atomicAdd(tie_cnt, 1);
      if (p < 4096) tie_idx[p] = i;
    }
  }
}

__global__ void tie_kernel(const uint* __restrict__ res2, const int* __restrict__ tie_cnt,
                           const int* __restrict__ tie_idx, unsigned char* __restrict__ msel)
{
  int need = (int)res2[1];
  int cnt = tie_cnt[0]; if (cnt > 4096) cnt = 4096;
  if (need <= 0) return;
  if (cnt <= need) {
    for (int i = threadIdx.x; i < cnt; i += 256) msel[tie_idx[i]] = 1;
  } else {
    for (int i = threadIdx.x; i < cnt; i += 256) {
      int my = tie_idx[i];
      int rank = 0;
      for (int j = 0; j < cnt; ++j) rank += (tie_idx[j] < my) ? 1 : 0;
      if (rank < need) msel[my] = 1;
    }
  }
}

__global__ void prune_kernel(const float* __restrict__ feats, const unsigned char* __restrict__ msel,
                             const void* __restrict__ mtrue, const int* __restrict__ flag,
                             float* __restrict__ dout)
{
  const unsigned char* mb = (const unsigned char*)mtrue;
  const int* mi = (const int*)mtrue;
  const bool bytes = (flag[0] != 0);
  float* pruned = dout + NOUTC;
  float* maskf  = dout + NOUTC + (size_t)NOUTC * 64;
  const float4* src = reinterpret_cast<const float4*>(feats);
  float4* dst = reinterpret_cast<float4*>(pruned);
  const int total = NOUTC * 16;
  for (int i = blockIdx.x * blockDim.x + threadIdx.x; i < total; i += gridDim.x * blockDim.x) {
    int n = i >> 4;
    bool mt = bytes ? (mb[n] != 0) : (mi[n] != 0);
    bool m = (msel[n] != 0) || mt;
    float4 v = src[i];
    float4 z = {0.f, 0.f, 0.f, 0.f};
    dst[i] = m ? v : z;
    if ((i & 15) == 0) maskf[n] = m ? 1.f : 0.f;
  }
}

// ---------------------------------------------------------------------------
extern "C" void kernel_launch(void* const* d_in, const int* in_sizes, int n_in,
                              void* d_out, int out_size, void* d_ws, size_t ws_size,
                              hipStream_t stream)
{
  const float* x    = (const float*)d_in[0];
  const float* Wup  = (const float*)d_in[1];
  const float* bup  = (const float*)d_in[2];
  const float* Wc0  = (const float*)d_in[3];
  const float* bc0  = (const float*)d_in[4];
  const float* W00  = (const float*)d_in[5];
  const float* b00  = (const float*)d_in[6];
  const float* W01  = (const float*)d_in[7];
  const float* b01  = (const float*)d_in[8];
  const float* W10  = (const float*)d_in[9];
  const float* b10  = (const float*)d_in[10];
  const float* W11  = (const float*)d_in[11];
  const float* b11  = (const float*)d_in[12];
  const float* W12  = (const float*)d_in[13];
  const float* b12  = (const float*)d_in[14];
  const float* Wcls = (const float*)d_in[15];
  const float* bcls = (const float*)d_in[16];
  const int*   nbr  = (const int*)d_in[17];
  const void*  mtrue= d_in[18];
  const int*   nums = (const int*)d_in[19];

  float* dout = (float*)d_out;

  float* fa   = (float*)d_ws;                               // (N+1)*64
  float* t0   = fa + (size_t)(NOUTC + 1) * 64;              // (N+1)*16
  float* t1   = t0 + (size_t)(NOUTC + 1) * 16;              // (N+1)*16
  float* g    = t0;                                         // cls overlay (dead by then)
  float* slab = t1 + (size_t)(NOUTC + 1) * 16;              // CAP*32 floats
  uint*  hist1 = (uint*)(slab + (size_t)CAP * 32);
  uint*  hist2 = hist1 + 65536;
  uint*  res1  = hist2 + 65536;
  uint*  res2  = res1 + 2;
  int*   tie_cnt = (int*)(res2 + 2);
  int*   flag    = tie_cnt + 1;
  int*   tie_idx = flag + 1;                                // 4096
  uint*  counts  = (uint*)(tie_idx + 4096);                 // 3456
  uint*  choff   = counts + 27 * NCH;                       // 3456
  int*   karr    = (int*)(choff + 27 * NCH);                // MAXB
  int*   meta    = karr + MAXB;                             // pad to even
  uint2* entries = (uint2*)(meta + 4);                      // CAP
  unsigned char* msel = (unsigned char*)(entries + CAP);    // NOUTC bytes
  float* fb = dout + NOUTC;   // (N+1)*64 parked in d_out's pruned+mask region

  init_kernel<<<512, 256, 0, stream>>>(hist1, hist2, tie_cnt, flag, fa, fb, t0, t1);
  detect_kernel<<<128, 256, 0, stream>>>((const unsigned char*)mtrue, flag);

  // build sparse-entry lists (shared by c0 and A convs)
  hipMemsetAsync(entries, 0xFF, (size_t)CAP * sizeof(uint2), stream);
  count_kernel<<<27 * NCH, 256, 0, stream>>>(nbr, counts);
  scan_kernel<<<1, 256, 0, stream>>>(counts, choff, karr);
  fill_kernel<<<27 * NCH, 256, 0, stream>>>(nbr, choff, entries);

  upsample_kernel<<<2048, 256, 0, stream>>>(x, Wup, bup, fa);

  // c0 = relu(sib + sparse + bc0)
  c0sib_kernel<<<1024, 256, 0, stream>>>(fa, Wc0, bc0, fb);
  p1c0_kernel<<<MAXB, 128, 0, stream>>>(fa, Wc0, entries, karr, slab, 0);
  cmbc0_kernel<<<256, 256, 0, stream>>>(nbr, choff, slab, fb, 0);
  p1c0_kernel<<<MAXB, 128, 0, stream>>>(fa, Wc0, entries, karr, slab, 1);
  cmbc0_kernel<<<256, 256, 0, stream>>>(nbr, choff, slab, fb, 1);

  const float* cur = fb; float* nxt = fa;
  for (int i = 0; i < 3; ++i) {
    const float* W00i = W00 + (size_t)i * 27 * 1024;
    // t0 = relu(spconv(cur, W00) + b00): sib + sparse + combine
    asib_kernel<<<512, 256, 0, stream>>>(cur, W00i, b00 + i * 16, t0);
    p1a_kernel<<<MAXB, 128, 0, stream>>>(cur, W00i, entries, karr, slab);
    cmba_kernel<<<128, 256, 0, stream>>>(nbr, choff, slab, t0);
    // t1 = relu(cur @ W10 + b10)
    spconv2<128, 64, 16, 4, 128, 1, true, true, false>
        <<<NOUTC / 128, 128, 0, stream>>>(cur, nullptr, W10 + (size_t)i * 1024,
                                          b10 + i * 16, nullptr, t1, 16, 0);
    // nxt[:,0:32] = spconv(t0, W01) + b01 + cur[:,0:32]
    spconv2<128, 16, 32, 4, 256, 27, false, false, true>
        <<<NOUTC / 128, 256, 0, stream>>>(t0, nbr, W01 + (size_t)i * 27 * 512,
                                          b01 + i * 32, cur, nxt, 64, 0);
    // t0 = relu(spconv(t1, W11) + b11)
    spconv2<128, 16, 16, 4, 128, 27, false, true, false>
        <<<NOUTC / 128, 128, 0, stream>>>(t1, nbr, W11 + (size_t)i * 27 * 256,
                                          b11 + i * 16, nullptr, t0, 16, 0);
    // nxt[:,32:64] = t0 @ W12 + b12 + cur[:,32:64]
    spconv2<128, 16, 32, 4, 256, 1, true, false, true>
        <<<NOUTC / 128, 256, 0, stream>>>(t0, nullptr, W12 + (size_t)i * 512,
                                          b12 + i * 32, cur, nxt, 64, 32);
    float* tmp = (float*)cur; cur = nxt; nxt = tmp;
  }
  // final features in fa

  cls1_kernel<<<512, 256, 0, stream>>>(cur, Wcls, g);
  cls2_kernel<<<512, 256, 0, stream>>>(g, nbr, bcls, dout);

  hist1_kernel<<<512, 256, 0, stream>>>(dout, hist1);
  scan1_kernel<<<1, 256, 0, stream>>>(hist1, nums, res1);
  hist2_kernel<<<512, 256, 0, stream>>>(dout, res1, hist2);
  scan2_kernel<<<1, 256, 0, stream>>>(hist2, res1, nums, res2);
  mark_kernel<<<512, 256, 0, stream>>>(dout, res2, msel, tie_cnt, tie_idx);
  tie_kernel<<<1, 256, 0, stream>>>(res2, tie_cnt, tie_idx, msel);
  prune_kernel<<<4096, 256, 0, stream>>>(cur, msel, mtrue, flag, dout);
}

// Round 8
// 1363.439 us; speedup vs baseline: 1.4354x; 1.0601x over previous
//
#include <hip/hip_runtime.h>
#include <cstdint>

#define NOUTC 131072
#define NINC  16384
#define CAP   204800        // sparse entry capacity (expected ~156K)
#define NCH   128           // chunks of 1024 rows
#define MAXB  3328          // phase1 grid (>= CAP/64)

using uint = unsigned int;

__device__ __forceinline__ uint fkey(float v){
  uint u = __float_as_uint(v);
  return (u & 0x80000000u) ? ~u : (u | 0x80000000u);
}

// tap index for output-child o gathering sibling q (d = q - o per dim)
__device__ __forceinline__ int ktap(int o, int q){
  int d0 = ((q>>2)&1) - ((o>>2)&1);
  int d1 = ((q>>1)&1) - ((o>>1)&1);
  int d2 = (q&1) - (o&1);
  return (d0+1)*9 + (d1+1)*3 + (d2+1);
}
// is tap k a guaranteed-sibling tap for child o?
__device__ __forceinline__ bool is_sib(int o, int k){
  int k0 = k/9, k1 = (k%9)/3, k2 = k%3;
  int q0 = ((o>>2)&1) + k0 - 1;
  int q1 = ((o>>1)&1) + k1 - 1;
  int q2 = (o&1)      + k2 - 1;
  return (q0>=0 && q0<=1 && q1>=0 && q1<=1 && q2>=0 && q2<=1);
}

// ---------------------------------------------------------------------------
// WW expansion preps: WW[(q*64+ci)][(o*CO+co)] = W[ktap(o,q)][ci][co]
// ---------------------------------------------------------------------------
__global__ __launch_bounds__(256)
void ww_prep_c0(const float* __restrict__ Wc0, float* __restrict__ WW)
{
  int tid = blockIdx.x * 256 + threadIdx.x;   // < 262144
  int col = tid & 511, rowk = tid >> 9;
  int o = col >> 6, co = col & 63;
  int q = rowk >> 6, ci = rowk & 63;
  WW[tid] = Wc0[ktap(o, q) * 4096 + ci * 64 + co];
}

__global__ __launch_bounds__(256)
void ww_prep_a(const float* __restrict__ W00i, float* __restrict__ WW2)
{
  int tid = blockIdx.x * 256 + threadIdx.x;   // < 65536
  int col = tid & 127, rowk = tid >> 7;
  int o = col >> 4, co = col & 15;
  int q = rowk >> 6, ci = rowk & 63;
  WW2[tid] = W00i[ktap(o, q) * 1024 + ci * 16 + co];
}

// ---------------------------------------------------------------------------
// Dense WW-GEMM: C[16384][N] = A[16384][512] @ B[512][N] + bias[col & BMASK]
// (no relu — sparse combine applies it later). K-chunked (KC=32), prefetch-
// ahead staging, 8-wide N tiles per thread, R2-proven LDS geometry.
// ---------------------------------------------------------------------------
template<int BLKM, int TM, int BMASK>
__global__ __launch_bounds__(256)
void gemm_ww(const float* __restrict__ A, const float* __restrict__ Bw,
             const float* __restrict__ bias, float* __restrict__ C, int N)
{
  constexpr int MGR  = BLKM / TM;
  constexpr int NGR  = 256 / MGR;
  constexpr int BLKN = NGR * 8;
  static_assert(MGR * NGR == 256, "bad tiling");
  constexpr int ASTR = BLKM + 4;
  constexpr int BSTR = BLKN + 4;
  constexpr int ALD  = BLKM / 32;     // float4 loads per thread (A chunk)
  constexpr int BLD  = BLKN / 32;     // float4 loads per thread (B chunk)
  __shared__ float As[32 * ASTR];
  __shared__ float Bs[32 * BSTR];

  const int t  = threadIdx.x;
  const int MBC = 16384 / BLKM;
  const int mb = blockIdx.x % MBC;
  const int nb = blockIdx.x / MBC;
  const int mg = t / NGR, ng = t % NGR;

  float4 ast[ALD], bst[BLD];
  float acc[TM][8];
  #pragma unroll
  for (int a = 0; a < TM; ++a)
    #pragma unroll
    for (int b = 0; b < 8; ++b) acc[a][b] = 0.f;

  auto load_a = [&](int kc){
    #pragma unroll
    for (int i2 = 0; i2 < ALD; ++i2){
      int idx = t + i2 * 256;
      int row = idx >> 3, c4 = idx & 7;
      ast[i2] = *reinterpret_cast<const float4*>(
          A + (size_t)(mb * BLKM + row) * 512 + kc * 32 + c4 * 4);
    }
  };
  auto load_b = [&](int kc){
    #pragma unroll
    for (int i2 = 0; i2 < BLD; ++i2){
      int idx = t + i2 * 256;
      int kk = idx >> 5, c4 = idx & 31;
      bst[i2] = *reinterpret_cast<const float4*>(
          Bw + (size_t)(kc * 32 + kk) * N + nb * BLKN + c4 * 4);
    }
  };

  load_a(0); load_b(0);

  for (int kc = 0; kc < 16; ++kc){
    #pragma unroll
    for (int i2 = 0; i2 < ALD; ++i2){
      int idx = t + i2 * 256;
      int row = idx >> 3, c4 = idx & 7;
      As[(c4*4+0)*ASTR + row] = ast[i2].x;
      As[(c4*4+1)*ASTR + row] = ast[i2].y;
      As[(c4*4+2)*ASTR + row] = ast[i2].z;
      As[(c4*4+3)*ASTR + row] = ast[i2].w;
    }
    #pragma unroll
    for (int i2 = 0; i2 < BLD; ++i2){
      int idx = t + i2 * 256;
      int kk = idx >> 5, c4 = idx & 31;
      *reinterpret_cast<float4*>(&Bs[kk * BSTR + c4 * 4]) = bst[i2];
    }
    __syncthreads();
    if (kc < 15){ load_a(kc + 1); load_b(kc + 1); }
    #pragma unroll 4
    for (int kk = 0; kk < 32; ++kk){
      float av[TM];
      if constexpr (TM == 8){
        float4 a0 = *reinterpret_cast<const float4*>(&As[kk*ASTR + mg*8]);
        float4 a1 = *reinterpret_cast<const float4*>(&As[kk*ASTR + mg*8 + 4]);
        av[0]=a0.x; av[1]=a0.y; av[2]=a0.z; av[3]=a0.w;
        av[4]=a1.x; av[5]=a1.y; av[6]=a1.z; av[7]=a1.w;
      } else {
        float4 a0 = *reinterpret_cast<const float4*>(&As[kk*ASTR + mg*4]);
        av[0]=a0.x; av[1]=a0.y; av[2]=a0.z; av[3]=a0.w;
      }
      float4 b0 = *reinterpret_cast<const float4*>(&Bs[kk*BSTR + ng*8]);
      float4 b1 = *reinterpret_cast<const float4*>(&Bs[kk*BSTR + ng*8 + 4]);
      float bv[8] = {b0.x,b0.y,b0.z,b0.w, b1.x,b1.y,b1.z,b1.w};
      #pragma unroll
      for (int a = 0; a < TM; ++a)
        #pragma unroll
        for (int b = 0; b < 8; ++b)
          acc[a][b] = fmaf(av[a], bv[b], acc[a][b]);
    }
    __syncthreads();
  }

  const int colbase = nb * BLKN + ng * 8;
  float bvals[8];
  #pragma unroll
  for (int b = 0; b < 8; ++b) bvals[b] = bias[(colbase + b) & BMASK];
  #pragma unroll
  for (int a = 0; a < TM; ++a){
    int row = mb * BLKM + mg * TM + a;
    float* dst = C + (size_t)row * N + colbase;
    float4 o0 = {acc[a][0]+bvals[0], acc[a][1]+bvals[1], acc[a][2]+bvals[2], acc[a][3]+bvals[3]};
    float4 o1 = {acc[a][4]+bvals[4], acc[a][5]+bvals[5], acc[a][6]+bvals[6], acc[a][7]+bvals[7]};
    *reinterpret_cast<float4*>(dst)     = o0;
    *reinterpret_cast<float4*>(dst + 4) = o1;
  }
}

// ---------------------------------------------------------------------------
// Sparse-entry list build: count -> scan -> fill (stable order => deterministic)
// ---------------------------------------------------------------------------
__global__ __launch_bounds__(256)
void count_kernel(const int* __restrict__ nbr, uint* __restrict__ counts)
{
  int k = blockIdx.x / NCH, cb = blockIdx.x % NCH;
  int t = threadIdx.x;
  int cnt = 0;
  for (int s = 0; s < 4; ++s){
    int row = cb*1024 + s*256 + t;
    int idx = nbr[(size_t)k*NOUTC + row];
    bool f = (idx != NOUTC) && !is_sib(row & 7, k);
    cnt += __syncthreads_count(f);
  }
  if (t == 0) counts[blockIdx.x] = (uint)cnt;
}

__global__ __launch_bounds__(256)
void scan_kernel(const uint* __restrict__ counts, uint* __restrict__ choff,
                 int* __restrict__ karr)
{
  __shared__ uint kt[27], segs[27], sege[27];
  int t = threadIdx.x;
  if (t < 27){ uint s = 0; for (int cb = 0; cb < NCH; ++cb) s += counts[t*NCH+cb]; kt[t] = s; }
  __syncthreads();
  if (t == 0){
    uint run = 0;
    for (int k = 0; k < 27; ++k){
      segs[k] = run;
      uint pad = (kt[k] + 63u) & ~63u;
      if (run + pad > CAP) pad = (run < CAP) ? ((CAP - run) & ~63u) : 0;
      run += pad;
      sege[k] = run;
    }
  }
  __syncthreads();
  if (t < 27){
    uint run = segs[t];
    for (int cb = 0; cb < NCH; ++cb){ choff[t*NCH+cb] = run; run += counts[t*NCH+cb]; }
  }
  __syncthreads();
  for (int b = t; b < MAXB; b += 256){
    int kk = -1; uint e = (uint)b * 64u;
    for (int k = 0; k < 27; ++k) if (e >= segs[k] && e < sege[k]) kk = k;
    karr[b] = kk;
  }
}

__global__ __launch_bounds__(256)
void fill_kernel(const int* __restrict__ nbr, const uint* __restrict__ choff,
                 uint2* __restrict__ entries)
{
  __shared__ uint wc[4][4];
  __shared__ uint sbase[4];
  int k = blockIdx.x / NCH, cb = blockIdx.x % NCH;
  int t = threadIdx.x, w = t >> 6, l = t & 63;
  uint base = choff[blockIdx.x];
  int rows[4], idxs[4];
  unsigned long long bal[4];
  for (int s = 0; s < 4; ++s){
    int row = cb*1024 + s*256 + t;
    int idx = nbr[(size_t)k*NOUTC + row];
    bool f = (idx != NOUTC) && !is_sib(row & 7, k);
    bal[s] = __ballot(f);
    if (l == 0) wc[s][w] = (uint)__popcll(bal[s]);
    rows[s] = row; idxs[s] = idx;
  }
  __syncthreads();
  if (t == 0){
    uint r = 0;
    for (int s = 0; s < 4; ++s){ sbase[s] = r; for (int w2 = 0; w2 < 4; ++w2) r += wc[s][w2]; }
  }
  __syncthreads();
  for (int s = 0; s < 4; ++s){
    if ((bal[s] >> l) & 1ull){
      uint off = sbase[s];
      for (int w2 = 0; w2 < w; ++w2) off += wc[s][w2];
      off += (uint)__popcll(bal[s] & ((1ull << l) - 1ull));
      uint pos = base + off;
      if (pos < CAP) entries[pos] = make_uint2((uint)rows[s], (uint)idxs[s]);
    }
  }
}

// ---------------------------------------------------------------------------
// Sparse phase1: 64 entries/block dense GEMM into slab (global slot = b*64+e)
// ---------------------------------------------------------------------------
__global__ __launch_bounds__(128)
void p1c0_kernel(const float* __restrict__ feats, const float* __restrict__ Wc0,
                 const uint2* __restrict__ entries, const int* __restrict__ karr,
                 float* __restrict__ slab, int h)
{
  __shared__ float ft2[64*68];
  __shared__ float wbs[64*36];
  int b = blockIdx.x;
  int k = karr[b];
  if (k < 0) return;
  int t = threadIdx.x;
  for (int e = t; e < 512; e += 128){
    int ci = e >> 3, c4 = e & 7;
    float4 v = *reinterpret_cast<const float4*>(Wc0 + (size_t)k*4096 + ci*64 + h*32 + c4*4);
    *reinterpret_cast<float4*>(&wbs[ci*36 + c4*4]) = v;
  }
  {
    int e = t >> 1, part = t & 1;
    uint2 en = entries[(size_t)b*64 + e];
    int gidx = (en.x == 0xFFFFFFFFu) ? NOUTC : (int)en.y;
    const float4* src = reinterpret_cast<const float4*>(feats + (size_t)gidx*64 + part*32);
    #pragma unroll
    for (int j = 0; j < 8; ++j){
      float4 v = src[j];
      int ci = part*32 + j*4;
      ft2[(ci+0)*68 + e] = v.x; ft2[(ci+1)*68 + e] = v.y;
      ft2[(ci+2)*68 + e] = v.z; ft2[(ci+3)*68 + e] = v.w;
    }
  }
  __syncthreads();
  int sp = t & 1, tile = t >> 1, eg = tile >> 3, cg = tile & 7;
  float acc[8][4];
  #pragma unroll
  for (int a = 0; a < 8; ++a){ acc[a][0]=0.f; acc[a][1]=0.f; acc[a][2]=0.f; acc[a][3]=0.f; }
  for (int i = 0; i < 32; ++i){
    int ci = sp + 2*i;
    float4 f0 = *reinterpret_cast<const float4*>(&ft2[ci*68 + eg*8]);
    float4 f1 = *reinterpret_cast<const float4*>(&ft2[ci*68 + eg*8 + 4]);
    float fv[8] = {f0.x,f0.y,f0.z,f0.w, f1.x,f1.y,f1.z,f1.w};
    float4 wv = *reinterpret_cast<const float4*>(&wbs[ci*36 + cg*4]);
    float wa[4] = {wv.x, wv.y, wv.z, wv.w};
    #pragma unroll
    for (int a = 0; a < 8; ++a)
      #pragma unroll
      for (int j = 0; j < 4; ++j)
        acc[a][j] = fmaf(fv[a], wa[j], acc[a][j]);
  }
  #pragma unroll
  for (int a = 0; a < 8; ++a)
    #pragma unroll
    for (int j = 0; j < 4; ++j) acc[a][j] += __shfl_xor(acc[a][j], 1, 64);
  if (sp == 0){
    #pragma unroll
    for (int a = 0; a < 8; ++a){
      int e = eg*8 + a;
      float4 v = {acc[a][0], acc[a][1], acc[a][2], acc[a][3]};
      *reinterpret_cast<float4*>(&slab[((size_t)b*64 + e)*32 + cg*4]) = v;
    }
  }
}

__global__ __launch_bounds__(128)
void p1a_kernel(const float* __restrict__ feats, const float* __restrict__ W00i,
                const uint2* __restrict__ entries, const int* __restrict__ karr,
                float* __restrict__ slab)
{
  __shared__ float ft2[64*68];
  __shared__ float wbs[64*18];
  int b = blockIdx.x;
  int k = karr[b];
  if (k < 0) return;
  int t = threadIdx.x;
  for (int e = t; e < 256; e += 128){
    int ci = e >> 2, c4 = e & 3;
    float4 v = *reinterpret_cast<const float4*>(W00i + (size_t)k*1024 + ci*16 + c4*4);
    *reinterpret_cast<float4*>(&wbs[ci*18 + c4*4]) = v;
  }
  {
    int e = t >> 1, part = t & 1;
    uint2 en = entries[(size_t)b*64 + e];
    int gidx = (en.x == 0xFFFFFFFFu) ? NOUTC : (int)en.y;
    const float4* src = reinterpret_cast<const float4*>(feats + (size_t)gidx*64 + part*32);
    #pragma unroll
    for (int j = 0; j < 8; ++j){
      float4 v = src[j];
      int ci = part*32 + j*4;
      ft2[(ci+0)*68 + e] = v.x; ft2[(ci+1)*68 + e] = v.y;
      ft2[(ci+2)*68 + e] = v.z; ft2[(ci+3)*68 + e] = v.w;
    }
  }
  __syncthreads();
  int sp = t & 1, tile = t >> 1, eg = tile >> 2, cg = tile & 3;
  float acc[4][4];
  #pragma unroll
  for (int a = 0; a < 4; ++a){ acc[a][0]=0.f; acc[a][1]=0.f; acc[a][2]=0.f; acc[a][3]=0.f; }
  for (int i = 0; i < 32; ++i){
    int ci = sp + 2*i;
    float4 f0 = *reinterpret_cast<const float4*>(&ft2[ci*68 + eg*4]);
    float fv[4] = {f0.x, f0.y, f0.z, f0.w};
    float4 wv = *reinterpret_cast<const float4*>(&wbs[ci*18 + cg*4]);
    float wa[4] = {wv.x, wv.y, wv.z, wv.w};
    #pragma unroll
    for (int a = 0; a < 4; ++a)
      #pragma unroll
      for (int j = 0; j < 4; ++j)
        acc[a][j] = fmaf(fv[a], wa[j], acc[a][j]);
  }
  #pragma unroll
  for (int a = 0; a < 4; ++a)
    #pragma unroll
    for (int j = 0; j < 4; ++j) acc[a][j] += __shfl_xor(acc[a][j], 1, 64);
  if (sp == 0){
    #pragma unroll
    for (int a = 0; a < 4; ++a){
      int e = eg*4 + a;
      float4 v = {acc[a][0], acc[a][1], acc[a][2], acc[a][3]};
      *reinterpret_cast<float4*>(&slab[((size_t)b*64 + e)*16 + cg*4]) = v;
    }
  }
}

// ---------------------------------------------------------------------------
// Combine: per-row exclusive; recomputes fill's stable ranks; adds slab; relu.
// ---------------------------------------------------------------------------
__global__ __launch_bounds__(256)
void cmbc0_kernel(const int* __restrict__ nbr, const uint* __restrict__ choff,
                  const float* __restrict__ slab, float* __restrict__ fb, int h)
{
  __shared__ uint wc[4][4];
  int cb = blockIdx.x >> 1, cq = blockIdx.x & 1;
  int t = threadIdx.x, w = t >> 6, l = t & 63;
  int co0 = h*32 + cq*16;
  float acc[4][16];
  #pragma unroll
  for (int s = 0; s < 4; ++s)
    #pragma unroll
    for (int j = 0; j < 16; ++j) acc[s][j] = 0.f;

  for (int k = 0; k < 27; ++k){
    unsigned long long bal[4];
    for (int s = 0; s < 4; ++s){
      int row = cb*1024 + s*256 + t;
      int idx = nbr[(size_t)k*NOUTC + row];
      bool f = (idx != NOUTC) && !is_sib(row & 7, k);
      bal[s] = __ballot(f);
      if (l == 0) wc[s][w] = (uint)__popcll(bal[s]);
    }
    __syncthreads();
    uint sbs[4];
    { uint r = 0; for (int s = 0; s < 4; ++s){ sbs[s] = r; for (int w2 = 0; w2 < 4; ++w2) r += wc[s][w2]; } }
    uint base = choff[k*NCH + cb];
    for (int s = 0; s < 4; ++s){
      if ((bal[s] >> l) & 1ull){
        uint off = sbs[s];
        for (int w2 = 0; w2 < w; ++w2) off += wc[s][w2];
        off += (uint)__popcll(bal[s] & ((1ull << l) - 1ull));
        uint pos = base + off;
        if (pos < CAP){
          const float4* sr = reinterpret_cast<const float4*>(slab + (size_t)pos*32 + cq*16);
          float4 a0 = sr[0], a1 = sr[1], a2 = sr[2], a3 = sr[3];
          acc[s][0]+=a0.x; acc[s][1]+=a0.y; acc[s][2]+=a0.z; acc[s][3]+=a0.w;
          acc[s][4]+=a1.x; acc[s][5]+=a1.y; acc[s][6]+=a1.z; acc[s][7]+=a1.w;
          acc[s][8]+=a2.x; acc[s][9]+=a2.y; acc[s][10]+=a2.z; acc[s][11]+=a2.w;
          acc[s][12]+=a3.x; acc[s][13]+=a3.y; acc[s][14]+=a3.z; acc[s][15]+=a3.w;
        }
      }
    }
    __syncthreads();
  }
  for (int s = 0; s < 4; ++s){
    int row = cb*1024 + s*256 + t;
    float* dst = fb + (size_t)row*64 + co0;
    #pragma unroll
    for (int m = 0; m < 4; ++m){
      float4 b0 = *reinterpret_cast<const float4*>(dst + m*4);
      float4 v;
      v.x = b0.x + acc[s][m*4+0]; v.x = v.x > 0.f ? v.x : 0.f;
      v.y = b0.y + acc[s][m*4+1]; v.y = v.y > 0.f ? v.y : 0.f;
      v.z = b0.z + acc[s][m*4+2]; v.z = v.z > 0.f ? v.z : 0.f;
      v.w = b0.w + acc[s][m*4+3]; v.w = v.w > 0.f ? v.w : 0.f;
      *reinterpret_cast<float4*>(dst + m*4) = v;
    }
  }
}

__global__ __launch_bounds__(256)
void cmba_kernel(const int* __restrict__ nbr, const uint* __restrict__ choff,
                 const float* __restrict__ slab, float* __restrict__ t0)
{
  __shared__ uint wc[4][4];
  int cb = blockIdx.x;
  int t = threadIdx.x, w = t >> 6, l = t & 63;
  float acc[4][16];
  #pragma unroll
  for (int s = 0; s < 4; ++s)
    #pragma unroll
    for (int j = 0; j < 16; ++j) acc[s][j] = 0.f;

  for (int k = 0; k < 27; ++k){
    unsigned long long bal[4];
    for (int s = 0; s < 4; ++s){
      int row = cb*1024 + s*256 + t;
      int idx = nbr[(size_t)k*NOUTC + row];
      bool f = (idx != NOUTC) && !is_sib(row & 7, k);
      bal[s] = __ballot(f);
      if (l == 0) wc[s][w] = (uint)__popcll(bal[s]);
    }
    __syncthreads();
    uint sbs[4];
    { uint r = 0; for (int s = 0; s < 4; ++s){ sbs[s] = r; for (int w2 = 0; w2 < 4; ++w2) r += wc[s][w2]; } }
    uint base = choff[k*NCH + cb];
    for (int s = 0; s < 4; ++s){
      if ((bal[s] >> l) & 1ull){
        uint off = sbs[s];
        for (int w2 = 0; w2 < w; ++w2) off += wc[s][w2];
        off += (uint)__popcll(bal[s] & ((1ull << l) - 1ull));
        uint pos = base + off;
        if (pos < CAP){
          const float4* sr = reinterpret_cast<const float4*>(slab + (size_t)pos*16);
          float4 a0 = sr[0], a1 = sr[1], a2 = sr[2], a3 = sr[3];
          acc[s][0]+=a0.x; acc[s][1]+=a0.y; acc[s][2]+=a0.z; acc[s][3]+=a0.w;
          acc[s][4]+=a1.x; acc[s][5]+=a1.y; acc[s][6]+=a1.z; acc[s][7]+=a1.w;
          acc[s][8]+=a2.x; acc[s][9]+=a2.y; acc[s][10]+=a2.z; acc[s][11]+=a2.w;
          acc[s][12]+=a3.x; acc[s][13]+=a3.y; acc[s][14]+=a3.z; acc[s][15]+=a3.w;
        }
      }
    }
    __syncthreads();
  }
  for (int s = 0; s < 4; ++s){
    int row = cb*1024 + s*256 + t;
    float* dst = t0 + (size_t)row*16;
    #pragma unroll
    for (int m = 0; m < 4; ++m){
      float4 b0 = *reinterpret_cast<const float4*>(dst + m*4);
      float4 v;
      v.x = b0.x + acc[s][m*4+0]; v.x = v.x > 0.f ? v.x : 0.f;
      v.y = b0.y + acc[s][m*4+1]; v.y = v.y > 0.f ? v.y : 0.f;
      v.z = b0.z + acc[s][m*4+2]; v.z = v.z > 0.f ? v.z : 0.f;
      v.w = b0.w + acc[s][m*4+3]; v.w = v.w > 0.f ? v.w : 0.f;
      *reinterpret_cast<float4*>(dst + m*4) = v;
    }
  }
}

// ---------------------------------------------------------------------------
// R2-proven spconv2 (used for W10, W01, W11, W12)
// ---------------------------------------------------------------------------
template<int ROWS, int CIN, int COUT, int SPLIT, int THREADS, int NK,
         bool IDENT, bool RELU, bool RESID>
__global__ __launch_bounds__(THREADS)
void spconv2(const float* __restrict__ feats, const int* __restrict__ nbr,
             const float* __restrict__ Wg, const float* __restrict__ bias,
             const float* __restrict__ resid, float* __restrict__ outp,
             int ostride, int coff)
{
  constexpr int RG = ROWS / 8, CG = COUT / 8;
  static_assert(RG * CG * SPLIT == THREADS, "bad thread tiling");
  constexpr int CIPT = CIN / SPLIT;
  constexpr int STR  = ROWS + 4;
  constexpr int WSTR = COUT + 4;
  constexpr int TPR  = THREADS / ROWS;
  constexpr int FSTG = CIN / TPR;
  constexpr int WSTG = (CIN * COUT) / THREADS;
  constexpr int NSLOT = THREADS / SPLIT;

  constexpr int MAIN_FL = CIN * STR + CIN * WSTR;
  constexpr int RED_FL  = (SPLIT > 1) ? (THREADS / 2) * 64 : 0;
  constexpr int LDS_FL  = MAIN_FL > RED_FL ? MAIN_FL : RED_FL;
  __shared__ float smem[LDS_FL];
  float* ft = smem;
  float* Wl = smem + CIN * STR;

  const int t    = threadIdx.x;
  const int base = blockIdx.x * ROWS;
  const int sp   = t % SPLIT;
  const int slot = t / SPLIT;
  const int rg = slot / CG, cg = slot % CG;
  const int trr = rg * 8, tcc = cg * 8;
  const int gr = t / TPR, part = t % TPR;

  float4 fstg[FSTG / 4];
  alignas(16) float wstg[WSTG];
  float acc[8][8];
  #pragma unroll
  for (int a = 0; a < 8; ++a)
    #pragma unroll
    for (int b = 0; b < 8; ++b) acc[a][b] = 0.f;

  auto load_f = [&](int k) {
    int gidx = IDENT ? (base + gr) : nbr[(size_t)k * NOUTC + base + gr];
    const float4* src = reinterpret_cast<const float4*>(feats + (size_t)gidx * CIN + part * FSTG);
    #pragma unroll
    for (int j = 0; j < FSTG / 4; ++j) fstg[j] = src[j];
  };
  auto load_w = [&](int k) {
    const float* wsrc = Wg + (size_t)k * CIN * COUT + t * WSTG;
    if constexpr (WSTG % 4 == 0) {
      #pragma unroll
      for (int m = 0; m < WSTG / 4; ++m)
        *reinterpret_cast<float4*>(&wstg[4 * m]) = reinterpret_cast<const float4*>(wsrc)[m];
    } else {
      *reinterpret_cast<float2*>(&wstg[0]) = *reinterpret_cast<const float2*>(wsrc);
    }
  };

  load_f(0); load_w(0);

  for (int k = 0; k < NK; ++k) {
    #pragma unroll
    for (int j = 0; j < FSTG / 4; ++j) {
      int ci = part * FSTG + 4 * j;
      ft[(ci + 0) * STR + gr] = fstg[j].x;
      ft[(ci + 1) * STR + gr] = fstg[j].y;
      ft[(ci + 2) * STR + gr] = fstg[j].z;
      ft[(ci + 3) * STR + gr] = fstg[j].w;
    }
    #pragma unroll
    for (int m = 0; m < WSTG; ++m) {
      int widx = t * WSTG + m;
      Wl[(widx / COUT) * WSTR + (widx % COUT)] = wstg[m];
    }
    __syncthreads();
    if (k + 1 < NK) { load_f(k + 1); load_w(k + 1); }
    #pragma unroll 4
    for (int i = 0; i < CIPT; ++i) {
      int ci = sp + SPLIT * i;
      float4 f0 = *reinterpret_cast<const float4*>(&ft[ci * STR + trr]);
      float4 f1 = *reinterpret_cast<const float4*>(&ft[ci * STR + trr + 4]);
      float4 w0 = *reinterpret_cast<const float4*>(&Wl[ci * WSTR + tcc]);
      float4 w1 = *reinterpret_cast<const float4*>(&Wl[ci * WSTR + tcc + 4]);
      float fv[8] = {f0.x, f0.y, f0.z, f0.w, f1.x, f1.y, f1.z, f1.w};
      float wv[8] = {w0.x, w0.y, w0.z, w0.w, w1.x, w1.y, w1.z, w1.w};
      #pragma unroll
      for (int a = 0; a < 8; ++a)
        #pragma unroll
        for (int b = 0; b < 8; ++b)
          acc[a][b] = fmaf(fv[a], wv[b], acc[a][b]);
    }
    __syncthreads();
  }

  if constexpr (SPLIT > 1) {
    float* red = smem;
    for (int off = SPLIT / 2; off >= 1; off >>= 1) {
      __syncthreads();
      if (sp >= off && sp < 2 * off) {
        float* dst = red + ((size_t)((sp - off) * NSLOT + slot)) * 64;
        #pragma unroll
        for (int a = 0; a < 8; ++a) {
          float4 v0 = {acc[a][0], acc[a][1], acc[a][2], acc[a][3]};
          float4 v1 = {acc[a][4], acc[a][5], acc[a][6], acc[a][7]};
          *reinterpret_cast<float4*>(dst + a * 8)     = v0;
          *reinterpret_cast<float4*>(dst + a * 8 + 4) = v1;
        }
      }
      __syncthreads();
      if (sp < off) {
        const float* s = red + ((size_t)(sp * NSLOT + slot)) * 64;
        #pragma unroll
        for (int a = 0; a < 8; ++a) {
          float4 v0 = *reinterpret_cast<const float4*>(s + a * 8);
          float4 v1 = *reinterpret_cast<const float4*>(s + a * 8 + 4);
          acc[a][0] += v0.x; acc[a][1] += v0.y; acc[a][2] += v0.z; acc[a][3] += v0.w;
          acc[a][4] += v1.x; acc[a][5] += v1.y; acc[a][6] += v1.z; acc[a][7] += v1.w;
        }
      }
    }
  }

  if (sp == 0) {
    #pragma unroll
    for (int a = 0; a < 8; ++a) {
      int r = base + trr + a;
      float o[8];
      #pragma unroll
      for (int b = 0; b < 8; ++b) {
        float v = acc[a][b] + bias[tcc + b];
        if (RELU) v = v > 0.f ? v : 0.f;
        o[b] = v;
      }
      if (RESID) {
        const float* rs = resid + (size_t)r * 64 + coff + tcc;
        float4 r0 = *reinterpret_cast<const float4*>(rs);
        float4 r1 = *reinterpret_cast<const float4*>(rs + 4);
        o[0] += r0.x; o[1] += r0.y; o[2] += r0.z; o[3] += r0.w;
        o[4] += r1.x; o[5] += r1.y; o[6] += r1.z; o[7] += r1.w;
      }
      float* dst = outp + (size_t)r * ostride + coff + tcc;
      float4 s0 = {o[0], o[1], o[2], o[3]};
      float4 s1 = {o[4], o[5], o[6], o[7]};
      *reinterpret_cast<float4*>(dst)     = s0;
      *reinterpret_cast<float4*>(dst + 4) = s1;
    }
  }
}

// ---------------------------------------------------------------------------
// upsample (R2)
// ---------------------------------------------------------------------------
__global__ __launch_bounds__(256)
void upsample_kernel(const float* __restrict__ x, const float* __restrict__ Wup,
                     const float* __restrict__ bup, float* __restrict__ outp)
{
  __shared__ float Wl[64 * 64];
  __shared__ float xt[64][68];
  const int t    = threadIdx.x;
  const int tile = blockIdx.x >> 3;
  const int k    = blockIdx.x & 7;
  const int base = tile * 64;

  #pragma unroll
  for (int i = t; i < 4096; i += 256) Wl[i] = Wup[k * 4096 + i];
  {
    const int gr = t >> 2, gp = t & 3;
    const float4* src = reinterpret_cast<const float4*>(x + (size_t)(base + gr) * 64) + gp * 4;
    #pragma unroll
    for (int j = 0; j < 4; ++j) {
      float4 v = src[j];
      int ci = (gp * 4 + j) * 4;
      xt[ci + 0][gr] = v.x; xt[ci + 1][gr] = v.y;
      xt[ci + 2][gr] = v.z; xt[ci + 3][gr] = v.w;
    }
  }
  __syncthreads();
  const int tcc = (t % 16) * 4, trr = (t / 16) * 4;
  float acc[4][4];
  #pragma unroll
  for (int a = 0; a < 4; ++a)
    #pragma unroll
    for (int b = 0; b < 4; ++b) acc[a][b] = 0.f;
  #pragma unroll
  for (int ci = 0; ci < 64; ++ci) {
    float4 f = *reinterpret_cast<const float4*>(&xt[ci][trr]);
    float4 w = *reinterpret_cast<const float4*>(&Wl[ci * 64 + tcc]);
    float fv[4] = {f.x, f.y, f.z, f.w};
    float wv[4] = {w.x, w.y, w.z, w.w};
    #pragma unroll
    for (int a = 0; a < 4; ++a)
      #pragma unroll
      for (int b = 0; b < 4; ++b) acc[a][b] = fmaf(fv[a], wv[b], acc[a][b]);
  }
  #pragma unroll
  for (int a = 0; a < 4; ++a) {
    int n = base + trr + a;
    float4 o;
    float v0 = acc[a][0] + bup[tcc + 0]; o.x = v0 > 0.f ? v0 : 0.f;
    float v1 = acc[a][1] + bup[tcc + 1]; o.y = v1 > 0.f ? v1 : 0.f;
    float v2 = acc[a][2] + bup[tcc + 2]; o.z = v2 > 0.f ? v2 : 0.f;
    float v3 = acc[a][3] + bup[tcc + 3]; o.w = v3 > 0.f ? v3 : 0.f;
    *reinterpret_cast<float4*>(outp + ((size_t)n * 8 + k) * 64 + tcc) = o;
  }
}

// ---------------------------------------------------------------------------
// cls / init / detect / topk / prune (unchanged)
// ---------------------------------------------------------------------------
__global__ __launch_bounds__(256)
void cls1_kernel(const float* __restrict__ feats, const float* __restrict__ Wcls,
                 float* __restrict__ g)
{
  const int n = blockIdx.x * 256 + threadIdx.x;
  if (blockIdx.x == 0 && threadIdx.x < 28) g[(size_t)NOUTC * 28 + threadIdx.x] = 0.f;
  const float4* src = reinterpret_cast<const float4*>(feats + (size_t)n * 64);
  float f[64];
  #pragma unroll
  for (int j = 0; j < 16; ++j) {
    float4 a = src[j];
    f[4*j+0]=a.x; f[4*j+1]=a.y; f[4*j+2]=a.z; f[4*j+3]=a.w;
  }
  #pragma unroll 1
  for (int k = 0; k < 27; ++k) {
    const float* w = Wcls + k * 64;
    float s0 = 0.f, s1 = 0.f, s2 = 0.f, s3 = 0.f;
    #pragma unroll
    for (int j = 0; j < 16; ++j) {
      s0 = fmaf(f[j],      w[j],      s0);
      s1 = fmaf(f[16 + j], w[16 + j], s1);
      s2 = fmaf(f[32 + j], w[32 + j], s2);
      s3 = fmaf(f[48 + j], w[48 + j], s3);
    }
    g[(size_t)n * 28 + k] = (s0 + s1) + (s2 + s3);
  }
}

__global__ __launch_bounds__(256)
void cls2_kernel(const float* __restrict__ g, const int* __restrict__ nbr,
                 const float* __restrict__ bcls, float* __restrict__ out_cls)
{
  const int n = blockIdx.x * 256 + threadIdx.x;
  float s = bcls[0];
  #pragma unroll 1
  for (int k = 0; k < 27; ++k) {
    int idx = nbr[(size_t)k * NOUTC + n];
    s += g[(size_t)idx * 28 + k];
  }
  out_cls[n] = s;
}

__global__ void init_kernel(uint* hist1, uint* hist2, int* tie_cnt, int* flag,
                            float* fa, float* fb, float* t0, float* t1)
{
  int i = blockIdx.x * 256 + threadIdx.x;
  if (i < 65536) hist1[i] = 0;
  else if (i < 131072) hist2[i - 65536] = 0;
  if (i == 0) { tie_cnt[0] = 0; flag[0] = 0; }
  if (i < 64) { fa[(size_t)NOUTC * 64 + i] = 0.f; fb[(size_t)NOUTC * 64 + i] = 0.f; }
  if (i < 16) { t0[(size_t)NOUTC * 16 + i] = 0.f; t1[(size_t)NOUTC * 16 + i] = 0.f; }
}

__global__ void detect_kernel(const unsigned char* __restrict__ mt, int* flag)
{
  int i = blockIdx.x * 256 + threadIdx.x;
  int p = i * 4 + 1;
  if (p < NOUTC && mt[p] != 0) flag[0] = 1;
}

__global__ void hist1_kernel(const float* __restrict__ cls, uint* __restrict__ hist)
{
  for (int i = blockIdx.x * blockDim.x + threadIdx.x; i < NOUTC; i += gridDim.x * blockDim.x)
    atomicAdd(&hist[fkey(cls[i]) >> 16], 1u);
}

__global__ void scan1_kernel(const uint* __restrict__ hist, const int* __restrict__ nums,
                             uint* __restrict__ res)
{
  __shared__ uint chunk[256];
  const int t = threadIdx.x;
  uint s = 0;
  for (int j = 0; j < 256; ++j) s += hist[t * 256 + j];
  chunk[t] = s;
  __syncthreads();
  if (t == 0) {
    uint k = (uint)nums[0];
    uint cum = 0; int c = 255;
    for (; c > 0; --c) { if (cum + chunk[c] >= k) break; cum += chunk[c]; }
    int B = c * 256; uint cum2 = cum;
    for (int b = c * 256 + 255; b >= c * 256; --b) {
      if (cum2 + hist[b] >= k) { B = b; break; }
      cum2 += hist[b];
    }
    res[0] = (uint)B; res[1] = cum2;
  }
}

__global__ void hist2_kernel(const float* __restrict__ cls, const uint* __restrict__ res1,
                             uint* __restrict__ hist)
{
  const uint B = res1[0];
  for (int i = blockIdx.x * blockDim.x + threadIdx.x; i < NOUTC; i += gridDim.x * blockDim.x) {
    uint key = fkey(cls[i]);
    if ((key >> 16) == B) atomicAdd(&hist[key & 0xffffu], 1u);
  }
}

__global__ void scan2_kernel(const uint* __restrict__ hist, const uint* __restrict__ res1,
                             const int* __restrict__ nums, uint* __restrict__ res2)
{
  __shared__ uint chunk[256];
  const int t = threadIdx.x;
  uint s = 0;
  for (int j = 0; j < 256; ++j) s += hist[t * 256 + j];
  chunk[t] = s;
  __syncthreads();
  if (t == 0) {
    uint k = (uint)nums[0];
    uint cum = res1[1]; int c = 255;
    for (; c > 0; --c) { if (cum + chunk[c] >= k) break; cum += chunk[c]; }
    int L = c * 256; uint cum2 = cum;
    for (int b = c * 256 + 255; b >= c * 256; --b) {
      if (cum2 + hist[b] >= k) { L = b; break; }
      cum2 += hist[b];
    }
    res2[0] = (res1[0] << 16) | (uint)L;
    res2[1] = k - cum2;
  }
}

__global__ void mark_kernel(const float* __restrict__ cls, const uint* __restrict__ res2,
                            unsigned char* __restrict__ msel, int* tie_cnt, int* tie_idx)
{
  const uint T = res2[0];
  for (int i = blockIdx.x * blockDim.x + threadIdx.x; i < NOUTC; i += gridDim.x * blockDim.x) {
    uint key = fkey(cls[i]);
    msel[i] = key > T ? 1 : 0;
    if (key == T) {
      int p = atomicAdd(tie_cnt, 1);
      if (p < 4096) tie_idx[p] = i;
    }
  }
}

__global__ void tie_kernel(const uint* __restrict__ res2, const int* __restrict__ tie_cnt,
                           const int* __restrict__ tie_idx, unsigned char* __restrict__ msel)
{
  int need = (int)res2[1];
  int cnt = tie_cnt[0]; if (cnt > 4096) cnt = 4096;
  if (need <= 0) return;
  if (cnt <= need) {
    for (int i = threadIdx.x; i < cnt; i += 256) msel[tie_idx[i]] = 1;
  } else {
    for (int i = threadIdx.x; i < cnt; i += 256) {
      int my = tie_idx[i];
      int rank = 0;
      for (int j = 0; j < cnt; ++j) rank += (tie_idx[j] < my) ? 1 : 0;
      if (rank < need) msel[my] = 1;
    }
  }
}

__global__ void prune_kernel(const float* __restrict__ feats, const unsigned char* __restrict__ msel,
                             const void* __restrict__ mtrue, const int* __restrict__ flag,
                             float* __restrict__ dout)
{
  const unsigned char* mb = (const unsigned char*)mtrue;
  const int* mi = (const int*)mtrue;
  const bool bytes = (flag[0] != 0);
  float* pruned = dout + NOUTC;
  float* maskf  = dout + NOUTC + (size_t)NOUTC * 64;
  const float4* src = reinterpret_cast<const float4*>(feats);
  float4* dst = reinterpret_cast<float4*>(pruned);
  const int total = NOUTC * 16;
  for (int i = blockIdx.x * blockDim.x + threadIdx.x; i < total; i += gridDim.x * blockDim.x) {
    int n = i >> 4;
    bool mt = bytes ? (mb[n] != 0) : (mi[n] != 0);
    bool m = (msel[n] != 0) || mt;
    float4 v = src[i];
    float4 z = {0.f, 0.f, 0.f, 0.f};
    dst[i] = m ? v : z;
    if ((i & 15) == 0) maskf[n] = m ? 1.f : 0.f;
  }
}

// ---------------------------------------------------------------------------
extern "C" void kernel_launch(void* const* d_in, const int* in_sizes, int n_in,
                              void* d_out, int out_size, void* d_ws, size_t ws_size,
                              hipStream_t stream)
{
  const float* x    = (const float*)d_in[0];
  const float* Wup  = (const float*)d_in[1];
  const float* bup  = (const float*)d_in[2];
  const float* Wc0  = (const float*)d_in[3];
  const float* bc0  = (const float*)d_in[4];
  const float* W00  = (const float*)d_in[5];
  const float* b00  = (const float*)d_in[6];
  const float* W01  = (const float*)d_in[7];
  const float* b01  = (const float*)d_in[8];
  const float* W10  = (const float*)d_in[9];
  const float* b10  = (const float*)d_in[10];
  const float* W11  = (const float*)d_in[11];
  const float* b11  = (const float*)d_in[12];
  const float* W12  = (const float*)d_in[13];
  const float* b12  = (const float*)d_in[14];
  const float* Wcls = (const float*)d_in[15];
  const float* bcls = (const float*)d_in[16];
  const int*   nbr  = (const int*)d_in[17];
  const void*  mtrue= d_in[18];
  const int*   nums = (const int*)d_in[19];

  float* dout = (float*)d_out;

  float* fa   = (float*)d_ws;                               // (N+1)*64
  float* t0   = fa + (size_t)(NOUTC + 1) * 64;              // (N+1)*16
  float* t1   = t0 + (size_t)(NOUTC + 1) * 16;              // (N+1)*16
  float* g    = t0;                                         // cls overlay (dead by then)
  float* slab = t1 + (size_t)(NOUTC + 1) * 16;              // CAP*32 floats
  uint*  hist1 = (uint*)(slab + (size_t)CAP * 32);
  uint*  hist2 = hist1 + 65536;
  uint*  res1  = hist2 + 65536;
  uint*  res2  = res1 + 2;
  int*   tie_cnt = (int*)(res2 + 2);
  int*   flag    = tie_cnt + 1;
  int*   tie_idx = flag + 1;                                // 4096
  uint*  counts  = (uint*)(tie_idx + 4096);                 // 3456
  uint*  choff   = counts + 27 * NCH;                       // 3456
  int*   karr    = (int*)(choff + 27 * NCH);                // MAXB
  int*   meta    = karr + MAXB;                             // pad
  uint2* entries = (uint2*)(meta + 4);                      // CAP
  unsigned char* msel = (unsigned char*)(entries + CAP);    // NOUTC bytes
  float* WW   = (float*)(msel + NOUTC);                     // 262144 floats
  float* WW2  = WW + 262144;                                // 3 * 65536 floats
  float* fb = dout + NOUTC;   // (N+1)*64 parked in d_out's pruned+mask region

  init_kernel<<<512, 256, 0, stream>>>(hist1, hist2, tie_cnt, flag, fa, fb, t0, t1);
  detect_kernel<<<128, 256, 0, stream>>>((const unsigned char*)mtrue, flag);

  // build sparse-entry lists + expanded sib weight matrices
  hipMemsetAsync(entries, 0xFF, (size_t)CAP * sizeof(uint2), stream);
  count_kernel<<<27 * NCH, 256, 0, stream>>>(nbr, counts);
  scan_kernel<<<1, 256, 0, stream>>>(counts, choff, karr);
  fill_kernel<<<27 * NCH, 256, 0, stream>>>(nbr, choff, entries);
  ww_prep_c0<<<1024, 256, 0, stream>>>(Wc0, WW);
  for (int i = 0; i < 3; ++i)
    ww_prep_a<<<256, 256, 0, stream>>>(W00 + (size_t)i * 27 * 1024, WW2 + (size_t)i * 65536);

  upsample_kernel<<<2048, 256, 0, stream>>>(x, Wup, bup, fa);

  // c0 = relu(sibGEMM + sparse + bc0)
  gemm_ww<128, 8, 63><<<512, 256, 0, stream>>>(fa, WW, bc0, fb, 512);
  p1c0_kernel<<<MAXB, 128, 0, stream>>>(fa, Wc0, entries, karr, slab, 0);
  cmbc0_kernel<<<256, 256, 0, stream>>>(nbr, choff, slab, fb, 0);
  p1c0_kernel<<<MAXB, 128, 0, stream>>>(fa, Wc0, entries, karr, slab, 1);
  cmbc0_kernel<<<256, 256, 0, stream>>>(nbr, choff, slab, fb, 1);

  const float* cur = fb; float* nxt = fa;
  for (int i = 0; i < 3; ++i) {
    const float* W00i = W00 + (size_t)i * 27 * 1024;
    // t0 = relu(spconv(cur, W00) + b00): sibGEMM + sparse + combine
    gemm_ww<64, 4, 15><<<256, 256, 0, stream>>>(cur, WW2 + (size_t)i * 65536,
                                                b00 + i * 16, t0, 128);
    p1a_kernel<<<MAXB, 128, 0, stream>>>(cur, W00i, entries, karr, slab);
    cmba_kernel<<<128, 256, 0, stream>>>(nbr, choff, slab, t0);
    // t1 = relu(cur @ W10 + b10)
    spconv2<128, 64, 16, 4, 128, 1, true, true, false>
        <<<NOUTC / 128, 128, 0, stream>>>(cur, nullptr, W10 + (size_t)i * 1024,
                                          b10 + i * 16, nullptr, t1, 16, 0);
    // nxt[:,0:32] = spconv(t0, W01) + b01 + cur[:,0:32]
    spconv2<128, 16, 32, 4, 256, 27, false, false, true>
        <<<NOUTC / 128, 256, 0, stream>>>(t0, nbr, W01 + (size_t)i * 27 * 512,
                                          b01 + i * 32, cur, nxt, 64, 0);
    // t0 = relu(spconv(t1, W11) + b11)
    spconv2<128, 16, 16, 4, 128, 27, false, true, false>
        <<<NOUTC / 128, 128, 0, stream>>>(t1, nbr, W11 + (size_t)i * 27 * 256,
                                          b11 + i * 16, nullptr, t0, 16, 0);
    // nxt[:,32:64] = t0 @ W12 + b12 + cur[:,32:64]
    spconv2<128, 16, 32, 4, 256, 1, true, false, true>
        <<<NOUTC / 128, 256, 0, stream>>>(t0, nullptr, W12 + (size_t)i * 512,
                                          b12 + i * 32, cur, nxt, 64, 32);
    float* tmp = (float*)cur; cur = nxt; nxt = tmp;
  }
  // final features in fa

  cls1_kernel<<<512, 256, 0, stream>>>(cur, Wcls, g);
  cls2_kernel<<<512, 256, 0, stream>>>(g, nbr, bcls, dout);

  hist1_kernel<<<512, 256, 0, stream>>>(dout, hist1);
  scan1_kernel<<<1, 256, 0, stream>>>(hist1, nums, res1);
  hist2_kernel<<<512, 256, 0, stream>>>(dout, res1, hist2);
  scan2_kernel<<<1, 256, 0, stream>>>(hist2, res1, nums, res2);
  mark_kernel<<<512, 256, 0, stream>>>(dout, res2, msel, tie_cnt, tie_idx);
  tie_kernel<<<1, 256, 0, stream>>>(res2, tie_cnt, tie_idx, msel);
  prune_kernel<<<4096, 256, 0, stream>>>(cur, msel, mtrue, flag, dout);
}

// Round 9
// 1357.630 us; speedup vs baseline: 1.4416x; 1.0043x over previous
//
#include <hip/hip_runtime.h>
#include <cstdint>

#define NOUTC 131072
#define NINC  16384
#define CAP   204800        // sparse entry capacity (expected ~156K)
#define NCH   128           // chunks of 1024 rows
#define MAXB  3328          // phase1 grid (>= CAP/64)

using uint = unsigned int;

__device__ __forceinline__ uint fkey(float v){
  uint u = __float_as_uint(v);
  return (u & 0x80000000u) ? ~u : (u | 0x80000000u);
}

// tap index for output-child o gathering sibling q (d = q - o per dim)
__device__ __forceinline__ int ktap(int o, int q){
  int d0 = ((q>>2)&1) - ((o>>2)&1);
  int d1 = ((q>>1)&1) - ((o>>1)&1);
  int d2 = (q&1) - (o&1);
  return (d0+1)*9 + (d1+1)*3 + (d2+1);
}
// is tap k a guaranteed-sibling tap for child o?
__device__ __forceinline__ bool is_sib(int o, int k){
  int k0 = k/9, k1 = (k%9)/3, k2 = k%3;
  int q0 = ((o>>2)&1) + k0 - 1;
  int q1 = ((o>>1)&1) + k1 - 1;
  int q2 = (o&1)      + k2 - 1;
  return (q0>=0 && q0<=1 && q1>=0 && q1<=1 && q2>=0 && q2<=1);
}

// ---------------------------------------------------------------------------
// WW expansion preps
// ---------------------------------------------------------------------------
__global__ __launch_bounds__(256)
void ww_prep_c0(const float* __restrict__ Wc0, float* __restrict__ WW)
{
  int tid = blockIdx.x * 256 + threadIdx.x;   // < 262144
  int col = tid & 511, rowk = tid >> 9;
  int o = col >> 6, co = col & 63;
  int q = rowk >> 6, ci = rowk & 63;
  WW[tid] = Wc0[ktap(o, q) * 4096 + ci * 64 + co];
}

// WW2 [512][256]: cols 0..127 = W00 sib expansion; cols 128..255 = blockdiag W10
__global__ __launch_bounds__(256)
void ww_prep_a2(const float* __restrict__ W00i, const float* __restrict__ W10i,
                float* __restrict__ WW2)
{
  int tid = blockIdx.x * 256 + threadIdx.x;   // < 131072
  int col = tid & 255, rowk = tid >> 8;
  int q = rowk >> 6, ci = rowk & 63;
  float v;
  if (col < 128){
    int o = col >> 4, co = col & 15;
    v = W00i[ktap(o, q) * 1024 + ci * 16 + co];
  } else {
    int c2 = col - 128;
    int o = c2 >> 4, co = c2 & 15;
    v = (q == o) ? W10i[ci * 16 + co] : 0.f;
  }
  WW2[tid] = v;
}

// ---------------------------------------------------------------------------
// gemm_ww v2: C[16384][N] = A[16384][512] @ B[512][N] (+bias), conflict-free.
// MGR=NGR=16 map: per-wave As reads broadcast (4 addrs), Bs reads 2-way (free).
// BLKN = 64. DUAL: cols<128 -> C (t0, no relu); cols>=128 -> C2 (t1, relu).
// ---------------------------------------------------------------------------
template<int TM, int BMASK, bool DUAL>
__global__ __launch_bounds__(256)
void gemm_ww2(const float* __restrict__ A, const float* __restrict__ Bw,
              const float* __restrict__ bias, const float* __restrict__ bias2,
              float* __restrict__ C, float* __restrict__ C2, int N)
{
  constexpr int BLKM = 16 * TM;
  constexpr int ASTR = BLKM + 4;
  constexpr int ALD  = BLKM / 32;
  __shared__ float As[32 * ASTR];
  __shared__ float Bs[32 * 68];

  const int t  = threadIdx.x;
  const int MBC = 16384 / BLKM;
  const int mb = blockIdx.x % MBC;
  const int nb = blockIdx.x / MBC;
  const int mg = t >> 4, ng = t & 15;

  float4 ast[ALD], bst[2];
  float acc[TM][4];
  #pragma unroll
  for (int a = 0; a < TM; ++a)
    #pragma unroll
    for (int b = 0; b < 4; ++b) acc[a][b] = 0.f;

  auto load_a = [&](int kc){
    #pragma unroll
    for (int i2 = 0; i2 < ALD; ++i2){
      int idx = t + i2 * 256;
      int row = idx >> 3, c4 = idx & 7;
      ast[i2] = *reinterpret_cast<const float4*>(
          A + (size_t)(mb * BLKM + row) * 512 + kc * 32 + c4 * 4);
    }
  };
  auto load_b = [&](int kc){
    #pragma unroll
    for (int i2 = 0; i2 < 2; ++i2){
      int idx = t + i2 * 256;
      int kk = idx >> 4, c4 = idx & 15;
      bst[i2] = *reinterpret_cast<const float4*>(
          Bw + (size_t)(kc * 32 + kk) * N + nb * 64 + c4 * 4);
    }
  };

  load_a(0); load_b(0);

  for (int kc = 0; kc < 16; ++kc){
    #pragma unroll
    for (int i2 = 0; i2 < ALD; ++i2){
      int idx = t + i2 * 256;
      int row = idx >> 3, c4 = idx & 7;
      As[(c4*4+0)*ASTR + row] = ast[i2].x;
      As[(c4*4+1)*ASTR + row] = ast[i2].y;
      As[(c4*4+2)*ASTR + row] = ast[i2].z;
      As[(c4*4+3)*ASTR + row] = ast[i2].w;
    }
    #pragma unroll
    for (int i2 = 0; i2 < 2; ++i2){
      int idx = t + i2 * 256;
      int kk = idx >> 4, c4 = idx & 15;
      *reinterpret_cast<float4*>(&Bs[kk * 68 + c4 * 4]) = bst[i2];
    }
    __syncthreads();
    if (kc < 15){ load_a(kc + 1); load_b(kc + 1); }
    #pragma unroll 4
    for (int kk = 0; kk < 32; ++kk){
      float av[TM];
      {
        float4 a0 = *reinterpret_cast<const float4*>(&As[kk*ASTR + mg*TM]);
        av[0]=a0.x; av[1]=a0.y; av[2]=a0.z; av[3]=a0.w;
        if constexpr (TM == 8){
          float4 a1 = *reinterpret_cast<const float4*>(&As[kk*ASTR + mg*TM + 4]);
          av[4]=a1.x; av[5]=a1.y; av[6]=a1.z; av[7]=a1.w;
        }
      }
      float4 b0 = *reinterpret_cast<const float4*>(&Bs[kk*68 + ng*4]);
      float bv[4] = {b0.x, b0.y, b0.z, b0.w};
      #pragma unroll
      for (int a = 0; a < TM; ++a)
        #pragma unroll
        for (int b = 0; b < 4; ++b)
          acc[a][b] = fmaf(av[a], bv[b], acc[a][b]);
    }
    __syncthreads();
  }

  const int colbase = nb * 64 + ng * 4;
  if (!DUAL || colbase < 128){
    const int stride = DUAL ? 128 : N;
    float bv[4];
    #pragma unroll
    for (int b = 0; b < 4; ++b) bv[b] = bias[(colbase + b) & BMASK];
    #pragma unroll
    for (int a = 0; a < TM; ++a){
      int row = mb * BLKM + mg * TM + a;
      float4 o = {acc[a][0]+bv[0], acc[a][1]+bv[1], acc[a][2]+bv[2], acc[a][3]+bv[3]};
      *reinterpret_cast<float4*>(C + (size_t)row * stride + colbase) = o;
    }
  } else {
    const int cb2 = colbase - 128;
    float bv[4];
    #pragma unroll
    for (int b = 0; b < 4; ++b) bv[b] = bias2[(cb2 + b) & 15];
    #pragma unroll
    for (int a = 0; a < TM; ++a){
      int row = mb * BLKM + mg * TM + a;
      float v0 = acc[a][0]+bv[0]; v0 = v0 > 0.f ? v0 : 0.f;
      float v1 = acc[a][1]+bv[1]; v1 = v1 > 0.f ? v1 : 0.f;
      float v2 = acc[a][2]+bv[2]; v2 = v2 > 0.f ? v2 : 0.f;
      float v3 = acc[a][3]+bv[3]; v3 = v3 > 0.f ? v3 : 0.f;
      float4 o = {v0, v1, v2, v3};
      *reinterpret_cast<float4*>(C2 + (size_t)row * 128 + cb2) = o;
    }
  }
}

// ---------------------------------------------------------------------------
// Sparse-entry list build: count -> scan -> fill (stable order => deterministic)
// ---------------------------------------------------------------------------
__global__ __launch_bounds__(256)
void count_kernel(const int* __restrict__ nbr, uint* __restrict__ counts)
{
  int k = blockIdx.x / NCH, cb = blockIdx.x % NCH;
  int t = threadIdx.x;
  int cnt = 0;
  for (int s = 0; s < 4; ++s){
    int row = cb*1024 + s*256 + t;
    int idx = nbr[(size_t)k*NOUTC + row];
    bool f = (idx != NOUTC) && !is_sib(row & 7, k);
    cnt += __syncthreads_count(f);
  }
  if (t == 0) counts[blockIdx.x] = (uint)cnt;
}

__global__ __launch_bounds__(256)
void scan_kernel(const uint* __restrict__ counts, uint* __restrict__ choff,
                 int* __restrict__ karr)
{
  __shared__ uint kt[27], segs[27], sege[27];
  int t = threadIdx.x;
  if (t < 27){ uint s = 0; for (int cb = 0; cb < NCH; ++cb) s += counts[t*NCH+cb]; kt[t] = s; }
  __syncthreads();
  if (t == 0){
    uint run = 0;
    for (int k = 0; k < 27; ++k){
      segs[k] = run;
      uint pad = (kt[k] + 63u) & ~63u;
      if (run + pad > CAP) pad = (run < CAP) ? ((CAP - run) & ~63u) : 0;
      run += pad;
      sege[k] = run;
    }
  }
  __syncthreads();
  if (t < 27){
    uint run = segs[t];
    for (int cb = 0; cb < NCH; ++cb){ choff[t*NCH+cb] = run; run += counts[t*NCH+cb]; }
  }
  __syncthreads();
  for (int b = t; b < MAXB; b += 256){
    int kk = -1; uint e = (uint)b * 64u;
    for (int k = 0; k < 27; ++k) if (e >= segs[k] && e < sege[k]) kk = k;
    karr[b] = kk;
  }
}

__global__ __launch_bounds__(256)
void fill_kernel(const int* __restrict__ nbr, const uint* __restrict__ choff,
                 uint2* __restrict__ entries)
{
  __shared__ uint wc[4][4];
  __shared__ uint sbase[4];
  int k = blockIdx.x / NCH, cb = blockIdx.x % NCH;
  int t = threadIdx.x, w = t >> 6, l = t & 63;
  uint base = choff[blockIdx.x];
  int rows[4], idxs[4];
  unsigned long long bal[4];
  for (int s = 0; s < 4; ++s){
    int row = cb*1024 + s*256 + t;
    int idx = nbr[(size_t)k*NOUTC + row];
    bool f = (idx != NOUTC) && !is_sib(row & 7, k);
    bal[s] = __ballot(f);
    if (l == 0) wc[s][w] = (uint)__popcll(bal[s]);
    rows[s] = row; idxs[s] = idx;
  }
  __syncthreads();
  if (t == 0){
    uint r = 0;
    for (int s = 0; s < 4; ++s){ sbase[s] = r; for (int w2 = 0; w2 < 4; ++w2) r += wc[s][w2]; }
  }
  __syncthreads();
  for (int s = 0; s < 4; ++s){
    if ((bal[s] >> l) & 1ull){
      uint off = sbase[s];
      for (int w2 = 0; w2 < w; ++w2) off += wc[s][w2];
      off += (uint)__popcll(bal[s] & ((1ull << l) - 1ull));
      uint pos = base + off;
      if (pos < CAP) entries[pos] = make_uint2((uint)rows[s], (uint)idxs[s]);
    }
  }
}

// ---------------------------------------------------------------------------
// Sparse phase1: 64 entries/block dense GEMM into slab (global slot = b*64+e)
// ---------------------------------------------------------------------------
__global__ __launch_bounds__(128)
void p1c0_kernel(const float* __restrict__ feats, const float* __restrict__ Wc0,
                 const uint2* __restrict__ entries, const int* __restrict__ karr,
                 float* __restrict__ slab, int h)
{
  __shared__ float ft2[64*68];
  __shared__ float wbs[64*36];
  int b = blockIdx.x;
  int k = karr[b];
  if (k < 0) return;
  int t = threadIdx.x;
  for (int e = t; e < 512; e += 128){
    int ci = e >> 3, c4 = e & 7;
    float4 v = *reinterpret_cast<const float4*>(Wc0 + (size_t)k*4096 + ci*64 + h*32 + c4*4);
    *reinterpret_cast<float4*>(&wbs[ci*36 + c4*4]) = v;
  }
  {
    int e = t >> 1, part = t & 1;
    uint2 en = entries[(size_t)b*64 + e];
    int gidx = (en.x == 0xFFFFFFFFu) ? NOUTC : (int)en.y;
    const float4* src = reinterpret_cast<const float4*>(feats + (size_t)gidx*64 + part*32);
    #pragma unroll
    for (int j = 0; j < 8; ++j){
      float4 v = src[j];
      int ci = part*32 + j*4;
      ft2[(ci+0)*68 + e] = v.x; ft2[(ci+1)*68 + e] = v.y;
      ft2[(ci+2)*68 + e] = v.z; ft2[(ci+3)*68 + e] = v.w;
    }
  }
  __syncthreads();
  int sp = t & 1, tile = t >> 1, eg = tile >> 3, cg = tile & 7;
  float acc[8][4];
  #pragma unroll
  for (int a = 0; a < 8; ++a){ acc[a][0]=0.f; acc[a][1]=0.f; acc[a][2]=0.f; acc[a][3]=0.f; }
  for (int i = 0; i < 32; ++i){
    int ci = sp + 2*i;
    float4 f0 = *reinterpret_cast<const float4*>(&ft2[ci*68 + eg*8]);
    float4 f1 = *reinterpret_cast<const float4*>(&ft2[ci*68 + eg*8 + 4]);
    float fv[8] = {f0.x,f0.y,f0.z,f0.w, f1.x,f1.y,f1.z,f1.w};
    float4 wv = *reinterpret_cast<const float4*>(&wbs[ci*36 + cg*4]);
    float wa[4] = {wv.x, wv.y, wv.z, wv.w};
    #pragma unroll
    for (int a = 0; a < 8; ++a)
      #pragma unroll
      for (int j = 0; j < 4; ++j)
        acc[a][j] = fmaf(fv[a], wa[j], acc[a][j]);
  }
  #pragma unroll
  for (int a = 0; a < 8; ++a)
    #pragma unroll
    for (int j = 0; j < 4; ++j) acc[a][j] += __shfl_xor(acc[a][j], 1, 64);
  if (sp == 0){
    #pragma unroll
    for (int a = 0; a < 8; ++a){
      int e = eg*8 + a;
      float4 v = {acc[a][0], acc[a][1], acc[a][2], acc[a][3]};
      *reinterpret_cast<float4*>(&slab[((size_t)b*64 + e)*32 + cg*4]) = v;
    }
  }
}

__global__ __launch_bounds__(128)
void p1a_kernel(const float* __restrict__ feats, const float* __restrict__ W00i,
                const uint2* __restrict__ entries, const int* __restrict__ karr,
                float* __restrict__ slab)
{
  __shared__ float ft2[64*68];
  __shared__ float wbs[64*18];
  int b = blockIdx.x;
  int k = karr[b];
  if (k < 0) return;
  int t = threadIdx.x;
  for (int e = t; e < 256; e += 128){
    int ci = e >> 2, c4 = e & 3;
    float4 v = *reinterpret_cast<const float4*>(W00i + (size_t)k*1024 + ci*16 + c4*4);
    *reinterpret_cast<float4*>(&wbs[ci*18 + c4*4]) = v;
  }
  {
    int e = t >> 1, part = t & 1;
    uint2 en = entries[(size_t)b*64 + e];
    int gidx = (en.x == 0xFFFFFFFFu) ? NOUTC : (int)en.y;
    const float4* src = reinterpret_cast<const float4*>(feats + (size_t)gidx*64 + part*32);
    #pragma unroll
    for (int j = 0; j < 8; ++j){
      float4 v = src[j];
      int ci = part*32 + j*4;
      ft2[(ci+0)*68 + e] = v.x; ft2[(ci+1)*68 + e] = v.y;
      ft2[(ci+2)*68 + e] = v.z; ft2[(ci+3)*68 + e] = v.w;
    }
  }
  __syncthreads();
  int sp = t & 1, tile = t >> 1, eg = tile >> 2, cg = tile & 3;
  float acc[4][4];
  #pragma unroll
  for (int a = 0; a < 4; ++a){ acc[a][0]=0.f; acc[a][1]=0.f; acc[a][2]=0.f; acc[a][3]=0.f; }
  for (int i = 0; i < 32; ++i){
    int ci = sp + 2*i;
    float4 f0 = *reinterpret_cast<const float4*>(&ft2[ci*68 + eg*4]);
    float fv[4] = {f0.x, f0.y, f0.z, f0.w};
    float4 wv = *reinterpret_cast<const float4*>(&wbs[ci*18 + cg*4]);
    float wa[4] = {wv.x, wv.y, wv.z, wv.w};
    #pragma unroll
    for (int a = 0; a < 4; ++a)
      #pragma unroll
      for (int j = 0; j < 4; ++j)
        acc[a][j] = fmaf(fv[a], wa[j], acc[a][j]);
  }
  #pragma unroll
  for (int a = 0; a < 4; ++a)
    #pragma unroll
    for (int j = 0; j < 4; ++j) acc[a][j] += __shfl_xor(acc[a][j], 1, 64);
  if (sp == 0){
    #pragma unroll
    for (int a = 0; a < 4; ++a){
      int e = eg*4 + a;
      float4 v = {acc[a][0], acc[a][1], acc[a][2], acc[a][3]};
      *reinterpret_cast<float4*>(&slab[((size_t)b*64 + e)*16 + cg*4]) = v;
    }
  }
}

// ---------------------------------------------------------------------------
// Combine: per-row exclusive; recomputes fill's stable ranks; adds slab; relu.
// ---------------------------------------------------------------------------
__global__ __launch_bounds__(256)
void cmbc0_kernel(const int* __restrict__ nbr, const uint* __restrict__ choff,
                  const float* __restrict__ slab, float* __restrict__ fb, int h)
{
  __shared__ uint wc[4][4];
  int cb = blockIdx.x >> 1, cq = blockIdx.x & 1;
  int t = threadIdx.x, w = t >> 6, l = t & 63;
  int co0 = h*32 + cq*16;
  float acc[4][16];
  #pragma unroll
  for (int s = 0; s < 4; ++s)
    #pragma unroll
    for (int j = 0; j < 16; ++j) acc[s][j] = 0.f;

  for (int k = 0; k < 27; ++k){
    unsigned long long bal[4];
    for (int s = 0; s < 4; ++s){
      int row = cb*1024 + s*256 + t;
      int idx = nbr[(size_t)k*NOUTC + row];
      bool f = (idx != NOUTC) && !is_sib(row & 7, k);
      bal[s] = __ballot(f);
      if (l == 0) wc[s][w] = (uint)__popcll(bal[s]);
    }
    __syncthreads();
    uint sbs[4];
    { uint r = 0; for (int s = 0; s < 4; ++s){ sbs[s] = r; for (int w2 = 0; w2 < 4; ++w2) r += wc[s][w2]; } }
    uint base = choff[k*NCH + cb];
    for (int s = 0; s < 4; ++s){
      if ((bal[s] >> l) & 1ull){
        uint off = sbs[s];
        for (int w2 = 0; w2 < w; ++w2) off += wc[s][w2];
        off += (uint)__popcll(bal[s] & ((1ull << l) - 1ull));
        uint pos = base + off;
        if (pos < CAP){
          const float4* sr = reinterpret_cast<const float4*>(slab + (size_t)pos*32 + cq*16);
          float4 a0 = sr[0], a1 = sr[1], a2 = sr[2], a3 = sr[3];
          acc[s][0]+=a0.x; acc[s][1]+=a0.y; acc[s][2]+=a0.z; acc[s][3]+=a0.w;
          acc[s][4]+=a1.x; acc[s][5]+=a1.y; acc[s][6]+=a1.z; acc[s][7]+=a1.w;
          acc[s][8]+=a2.x; acc[s][9]+=a2.y; acc[s][10]+=a2.z; acc[s][11]+=a2.w;
          acc[s][12]+=a3.x; acc[s][13]+=a3.y; acc[s][14]+=a3.z; acc[s][15]+=a3.w;
        }
      }
    }
    __syncthreads();
  }
  for (int s = 0; s < 4; ++s){
    int row = cb*1024 + s*256 + t;
    float* dst = fb + (size_t)row*64 + co0;
    #pragma unroll
    for (int m = 0; m < 4; ++m){
      float4 b0 = *reinterpret_cast<const float4*>(dst + m*4);
      float4 v;
      v.x = b0.x + acc[s][m*4+0]; v.x = v.x > 0.f ? v.x : 0.f;
      v.y = b0.y + acc[s][m*4+1]; v.y = v.y > 0.f ? v.y : 0.f;
      v.z = b0.z + acc[s][m*4+2]; v.z = v.z > 0.f ? v.z : 0.f;
      v.w = b0.w + acc[s][m*4+3]; v.w = v.w > 0.f ? v.w : 0.f;
      *reinterpret_cast<float4*>(dst + m*4) = v;
    }
  }
}

__global__ __launch_bounds__(256)
void cmba_kernel(const int* __restrict__ nbr, const uint* __restrict__ choff,
                 const float* __restrict__ slab, float* __restrict__ t0)
{
  __shared__ uint wc[4][4];
  int cb = blockIdx.x;
  int t = threadIdx.x, w = t >> 6, l = t & 63;
  float acc[4][16];
  #pragma unroll
  for (int s = 0; s < 4; ++s)
    #pragma unroll
    for (int j = 0; j < 16; ++j) acc[s][j] = 0.f;

  for (int k = 0; k < 27; ++k){
    unsigned long long bal[4];
    for (int s = 0; s < 4; ++s){
      int row = cb*1024 + s*256 + t;
      int idx = nbr[(size_t)k*NOUTC + row];
      bool f = (idx != NOUTC) && !is_sib(row & 7, k);
      bal[s] = __ballot(f);
      if (l == 0) wc[s][w] = (uint)__popcll(bal[s]);
    }
    __syncthreads();
    uint sbs[4];
    { uint r = 0; for (int s = 0; s < 4; ++s){ sbs[s] = r; for (int w2 = 0; w2 < 4; ++w2) r += wc[s][w2]; } }
    uint base = choff[k*NCH + cb];
    for (int s = 0; s < 4; ++s){
      if ((bal[s] >> l) & 1ull){
        uint off = sbs[s];
        for (int w2 = 0; w2 < w; ++w2) off += wc[s][w2];
        off += (uint)__popcll(bal[s] & ((1ull << l) - 1ull));
        uint pos = base + off;
        if (pos < CAP){
          const float4* sr = reinterpret_cast<const float4*>(slab + (size_t)pos*16);
          float4 a0 = sr[0], a1 = sr[1], a2 = sr[2], a3 = sr[3];
          acc[s][0]+=a0.x; acc[s][1]+=a0.y; acc[s][2]+=a0.z; acc[s][3]+=a0.w;
          acc[s][4]+=a1.x; acc[s][5]+=a1.y; acc[s][6]+=a1.z; acc[s][7]+=a1.w;
          acc[s][8]+=a2.x; acc[s][9]+=a2.y; acc[s][10]+=a2.z; acc[s][11]+=a2.w;
          acc[s][12]+=a3.x; acc[s][13]+=a3.y; acc[s][14]+=a3.z; acc[s][15]+=a3.w;
        }
      }
    }
    __syncthreads();
  }
  for (int s = 0; s < 4; ++s){
    int row = cb*1024 + s*256 + t;
    float* dst = t0 + (size_t)row*16;
    #pragma unroll
    for (int m = 0; m < 4; ++m){
      float4 b0 = *reinterpret_cast<const float4*>(dst + m*4);
      float4 v;
      v.x = b0.x + acc[s][m*4+0]; v.x = v.x > 0.f ? v.x : 0.f;
      v.y = b0.y + acc[s][m*4+1]; v.y = v.y > 0.f ? v.y : 0.f;
      v.z = b0.z + acc[s][m*4+2]; v.z = v.z > 0.f ? v.z : 0.f;
      v.w = b0.w + acc[s][m*4+3]; v.w = v.w > 0.f ? v.w : 0.f;
      *reinterpret_cast<float4*>(dst + m*4) = v;
    }
  }
}

// ---------------------------------------------------------------------------
// R2-proven spconv2 (used for W01, W11, W12)
// ---------------------------------------------------------------------------
template<int ROWS, int CIN, int COUT, int SPLIT, int THREADS, int NK,
         bool IDENT, bool RELU, bool RESID>
__global__ __launch_bounds__(THREADS)
void spconv2(const float* __restrict__ feats, const int* __restrict__ nbr,
             const float* __restrict__ Wg, const float* __restrict__ bias,
             const float* __restrict__ resid, float* __restrict__ outp,
             int ostride, int coff)
{
  constexpr int RG = ROWS / 8, CG = COUT / 8;
  static_assert(RG * CG * SPLIT == THREADS, "bad thread tiling");
  constexpr int CIPT = CIN / SPLIT;
  constexpr int STR  = ROWS + 4;
  constexpr int WSTR = COUT + 4;
  constexpr int TPR  = THREADS / ROWS;
  constexpr int FSTG = CIN / TPR;
  constexpr int WSTG = (CIN * COUT) / THREADS;
  constexpr int NSLOT = THREADS / SPLIT;

  constexpr int MAIN_FL = CIN * STR + CIN * WSTR;
  constexpr int RED_FL  = (SPLIT > 1) ? (THREADS / 2) * 64 : 0;
  constexpr int LDS_FL  = MAIN_FL > RED_FL ? MAIN_FL : RED_FL;
  __shared__ float smem[LDS_FL];
  float* ft = smem;
  float* Wl = smem + CIN * STR;

  const int t    = threadIdx.x;
  const int base = blockIdx.x * ROWS;
  const int sp   = t % SPLIT;
  const int slot = t / SPLIT;
  const int rg = slot / CG, cg = slot % CG;
  const int trr = rg * 8, tcc = cg * 8;
  const int gr = t / TPR, part = t % TPR;

  float4 fstg[FSTG / 4];
  alignas(16) float wstg[WSTG];
  float acc[8][8];
  #pragma unroll
  for (int a = 0; a < 8; ++a)
    #pragma unroll
    for (int b = 0; b < 8; ++b) acc[a][b] = 0.f;

  auto load_f = [&](int k) {
    int gidx = IDENT ? (base + gr) : nbr[(size_t)k * NOUTC + base + gr];
    const float4* src = reinterpret_cast<const float4*>(feats + (size_t)gidx * CIN + part * FSTG);
    #pragma unroll
    for (int j = 0; j < FSTG / 4; ++j) fstg[j] = src[j];
  };
  auto load_w = [&](int k) {
    const float* wsrc = Wg + (size_t)k * CIN * COUT + t * WSTG;
    if constexpr (WSTG % 4 == 0) {
      #pragma unroll
      for (int m = 0; m < WSTG / 4; ++m)
        *reinterpret_cast<float4*>(&wstg[4 * m]) = reinterpret_cast<const float4*>(wsrc)[m];
    } else {
      *reinterpret_cast<float2*>(&wstg[0]) = *reinterpret_cast<const float2*>(wsrc);
    }
  };

  load_f(0); load_w(0);

  for (int k = 0; k < NK; ++k) {
    #pragma unroll
    for (int j = 0; j < FSTG / 4; ++j) {
      int ci = part * FSTG + 4 * j;
      ft[(ci + 0) * STR + gr] = fstg[j].x;
      ft[(ci + 1) * STR + gr] = fstg[j].y;
      ft[(ci + 2) * STR + gr] = fstg[j].z;
      ft[(ci + 3) * STR + gr] = fstg[j].w;
    }
    #pragma unroll
    for (int m = 0; m < WSTG; ++m) {
      int widx = t * WSTG + m;
      Wl[(widx / COUT) * WSTR + (widx % COUT)] = wstg[m];
    }
    __syncthreads();
    if (k + 1 < NK) { load_f(k + 1); load_w(k + 1); }
    #pragma unroll 4
    for (int i = 0; i < CIPT; ++i) {
      int ci = sp + SPLIT * i;
      float4 f0 = *reinterpret_cast<const float4*>(&ft[ci * STR + trr]);
      float4 f1 = *reinterpret_cast<const float4*>(&ft[ci * STR + trr + 4]);
      float4 w0 = *reinterpret_cast<const float4*>(&Wl[ci * WSTR + tcc]);
      float4 w1 = *reinterpret_cast<const float4*>(&Wl[ci * WSTR + tcc + 4]);
      float fv[8] = {f0.x, f0.y, f0.z, f0.w, f1.x, f1.y, f1.z, f1.w};
      float wv[8] = {w0.x, w0.y, w0.z, w0.w, w1.x, w1.y, w1.z, w1.w};
      #pragma unroll
      for (int a = 0; a < 8; ++a)
        #pragma unroll
        for (int b = 0; b < 8; ++b)
          acc[a][b] = fmaf(fv[a], wv[b], acc[a][b]);
    }
    __syncthreads();
  }

  if constexpr (SPLIT > 1) {
    float* red = smem;
    for (int off = SPLIT / 2; off >= 1; off >>= 1) {
      __syncthreads();
      if (sp >= off && sp < 2 * off) {
        float* dst = red + ((size_t)((sp - off) * NSLOT + slot)) * 64;
        #pragma unroll
        for (int a = 0; a < 8; ++a) {
          float4 v0 = {acc[a][0], acc[a][1], acc[a][2], acc[a][3]};
          float4 v1 = {acc[a][4], acc[a][5], acc[a][6], acc[a][7]};
          *reinterpret_cast<float4*>(dst + a * 8)     = v0;
          *reinterpret_cast<float4*>(dst + a * 8 + 4) = v1;
        }
      }
      __syncthreads();
      if (sp < off) {
        const float* s = red + ((size_t)(sp * NSLOT + slot)) * 64;
        #pragma unroll
        for (int a = 0; a < 8; ++a) {
          float4 v0 = *reinterpret_cast<const float4*>(s + a * 8);
          float4 v1 = *reinterpret_cast<const float4*>(s + a * 8 + 4);
          acc[a][0] += v0.x; acc[a][1] += v0.y; acc[a][2] += v0.z; acc[a][3] += v0.w;
          acc[a][4] += v1.x; acc[a][5] += v1.y; acc[a][6] += v1.z; acc[a][7] += v1.w;
        }
      }
    }
  }

  if (sp == 0) {
    #pragma unroll
    for (int a = 0; a < 8; ++a) {
      int r = base + trr + a;
      float o[8];
      #pragma unroll
      for (int b = 0; b < 8; ++b) {
        float v = acc[a][b] + bias[tcc + b];
        if (RELU) v = v > 0.f ? v : 0.f;
        o[b] = v;
      }
      if (RESID) {
        const float* rs = resid + (size_t)r * 64 + coff + tcc;
        float4 r0 = *reinterpret_cast<const float4*>(rs);
        float4 r1 = *reinterpret_cast<const float4*>(rs + 4);
        o[0] += r0.x; o[1] += r0.y; o[2] += r0.z; o[3] += r0.w;
        o[4] += r1.x; o[5] += r1.y; o[6] += r1.z; o[7] += r1.w;
      }
      float* dst = outp + (size_t)r * ostride + coff + tcc;
      float4 s0 = {o[0], o[1], o[2], o[3]};
      float4 s1 = {o[4], o[5], o[6], o[7]};
      *reinterpret_cast<float4*>(dst)     = s0;
      *reinterpret_cast<float4*>(dst + 4) = s1;
    }
  }
}

// ---------------------------------------------------------------------------
// upsample (R2)
// ---------------------------------------------------------------------------
__global__ __launch_bounds__(256)
void upsample_kernel(const float* __restrict__ x, const float* __restrict__ Wup,
                     const float* __restrict__ bup, float* __restrict__ outp)
{
  __shared__ float Wl[64 * 64];
  __shared__ float xt[64][68];
  const int t    = threadIdx.x;
  const int tile = blockIdx.x >> 3;
  const int k    = blockIdx.x & 7;
  const int base = tile * 64;

  #pragma unroll
  for (int i = t; i < 4096; i += 256) Wl[i] = Wup[k * 4096 + i];
  {
    const int gr = t >> 2, gp = t & 3;
    const float4* src = reinterpret_cast<const float4*>(x + (size_t)(base + gr) * 64) + gp * 4;
    #pragma unroll
    for (int j = 0; j < 4; ++j) {
      float4 v = src[j];
      int ci = (gp * 4 + j) * 4;
      xt[ci + 0][gr] = v.x; xt[ci + 1][gr] = v.y;
      xt[ci + 2][gr] = v.z; xt[ci + 3][gr] = v.w;
    }
  }
  __syncthreads();
  const int tcc = (t % 16) * 4, trr = (t / 16) * 4;
  float acc[4][4];
  #pragma unroll
  for (int a = 0; a < 4; ++a)
    #pragma unroll
    for (int b = 0; b < 4; ++b) acc[a][b] = 0.f;
  #pragma unroll
  for (int ci = 0; ci < 64; ++ci) {
    float4 f = *reinterpret_cast<const float4*>(&xt[ci][trr]);
    float4 w = *reinterpret_cast<const float4*>(&Wl[ci * 64 + tcc]);
    float fv[4] = {f.x, f.y, f.z, f.w};
    float wv[4] = {w.x, w.y, w.z, w.w};
    #pragma unroll
    for (int a = 0; a < 4; ++a)
      #pragma unroll
      for (int b = 0; b < 4; ++b) acc[a][b] = fmaf(fv[a], wv[b], acc[a][b]);
  }
  #pragma unroll
  for (int a = 0; a < 4; ++a) {
    int n = base + trr + a;
    float4 o;
    float v0 = acc[a][0] + bup[tcc + 0]; o.x = v0 > 0.f ? v0 : 0.f;
    float v1 = acc[a][1] + bup[tcc + 1]; o.y = v1 > 0.f ? v1 : 0.f;
    float v2 = acc[a][2] + bup[tcc + 2]; o.z = v2 > 0.f ? v2 : 0.f;
    float v3 = acc[a][3] + bup[tcc + 3]; o.w = v3 > 0.f ? v3 : 0.f;
    *reinterpret_cast<float4*>(outp + ((size_t)n * 8 + k) * 64 + tcc) = o;
  }
}

// ---------------------------------------------------------------------------
// cls / init / detect / topk / prune (unchanged)
// ---------------------------------------------------------------------------
__global__ __launch_bounds__(256)
void cls1_kernel(const float* __restrict__ feats, const float* __restrict__ Wcls,
                 float* __restrict__ g)
{
  const int n = blockIdx.x * 256 + threadIdx.x;
  if (blockIdx.x == 0 && threadIdx.x < 28) g[(size_t)NOUTC * 28 + threadIdx.x] = 0.f;
  const float4* src = reinterpret_cast<const float4*>(feats + (size_t)n * 64);
  float f[64];
  #pragma unroll
  for (int j = 0; j < 16; ++j) {
    float4 a = src[j];
    f[4*j+0]=a.x; f[4*j+1]=a.y; f[4*j+2]=a.z; f[4*j+3]=a.w;
  }
  #pragma unroll 1
  for (int k = 0; k < 27; ++k) {
    const float* w = Wcls + k * 64;
    float s0 = 0.f, s1 = 0.f, s2 = 0.f, s3 = 0.f;
    #pragma unroll
    for (int j = 0; j < 16; ++j) {
      s0 = fmaf(f[j],      w[j],      s0);
      s1 = fmaf(f[16 + j], w[16 + j], s1);
      s2 = fmaf(f[32 + j], w[32 + j], s2);
      s3 = fmaf(f[48 + j], w[48 + j], s3);
    }
    g[(size_t)n * 28 + k] = (s0 + s1) + (s2 + s3);
  }
}

__global__ __launch_bounds__(256)
void cls2_kernel(const float* __restrict__ g, const int* __restrict__ nbr,
                 const float* __restrict__ bcls, float* __restrict__ out_cls)
{
  const int n = blockIdx.x * 256 + threadIdx.x;
  float s = bcls[0];
  #pragma unroll 1
  for (int k = 0; k < 27; ++k) {
    int idx = nbr[(size_t)k * NOUTC + n];
    s += g[(size_t)idx * 28 + k];
  }
  out_cls[n] = s;
}

__global__ void init_kernel(uint* hist1, uint* hist2, int* tie_cnt, int* flag,
                            float* fa, float* fb, float* t0, float* t1)
{
  int i = blockIdx.x * 256 + threadIdx.x;
  if (i < 65536) hist1[i] = 0;
  else if (i < 131072) hist2[i - 65536] = 0;
  if (i == 0) { tie_cnt[0] = 0; flag[0] = 0; }
  if (i < 64) { fa[(size_t)NOUTC * 64 + i] = 0.f; fb[(size_t)NOUTC * 64 + i] = 0.f; }
  if (i < 16) { t0[(size_t)NOUTC * 16 + i] = 0.f; t1[(size_t)NOUTC * 16 + i] = 0.f; }
}

__global__ void detect_kernel(const unsigned char* __restrict__ mt, int* flag)
{
  int i = blockIdx.x * 256 + threadIdx.x;
  int p = i * 4 + 1;
  if (p < NOUTC && mt[p] != 0) flag[0] = 1;
}

__global__ void hist1_kernel(const float* __restrict__ cls, uint* __restrict__ hist)
{
  for (int i = blockIdx.x * blockDim.x + threadIdx.x; i < NOUTC; i += gridDim.x * blockDim.x)
    atomicAdd(&hist[fkey(cls[i]) >> 16], 1u);
}

__global__ void scan1_kernel(const uint* __restrict__ hist, const int* __restrict__ nums,
                             uint* __restrict__ res)
{
  __shared__ uint chunk[256];
  const int t = threadIdx.x;
  uint s = 0;
  for (int j = 0; j < 256; ++j) s += hist[t * 256 + j];
  chunk[t] = s;
  __syncthreads();
  if (t == 0) {
    uint k = (uint)nums[0];
    uint cum = 0; int c = 255;
    for (; c > 0; --c) { if (cum + chunk[c] >= k) break; cum += chunk[c]; }
    int B = c * 256; uint cum2 = cum;
    for (int b = c * 256 + 255; b >= c * 256; --b) {
      if (cum2 + hist[b] >= k) { B = b; break; }
      cum2 += hist[b];
    }
    res[0] = (uint)B; res[1] = cum2;
  }
}

__global__ void hist2_kernel(const float* __restrict__ cls, const uint* __restrict__ res1,
                             uint* __restrict__ hist)
{
  const uint B = res1[0];
  for (int i = blockIdx.x * blockDim.x + threadIdx.x; i < NOUTC; i += gridDim.x * blockDim.x) {
    uint key = fkey(cls[i]);
    if ((key >> 16) == B) atomicAdd(&hist[key & 0xffffu], 1u);
  }
}

__global__ void scan2_kernel(const uint* __restrict__ hist, const uint* __restrict__ res1,
                             const int* __restrict__ nums, uint* __restrict__ res2)
{
  __shared__ uint chunk[256];
  const int t = threadIdx.x;
  uint s = 0;
  for (int j = 0; j < 256; ++j) s += hist[t * 256 + j];
  chunk[t] = s;
  __syncthreads();
  if (t == 0) {
    uint k = (uint)nums[0];
    uint cum = res1[1]; int c = 255;
    for (; c > 0; --c) { if (cum + chunk[c] >= k) break; cum += chunk[c]; }
    int L = c * 256; uint cum2 = cum;
    for (int b = c * 256 + 255; b >= c * 256; --b) {
      if (cum2 + hist[b] >= k) { L = b; break; }
      cum2 += hist[b];
    }
    res2[0] = (res1[0] << 16) | (uint)L;
    res2[1] = k - cum2;
  }
}

__global__ void mark_kernel(const float* __restrict__ cls, const uint* __restrict__ res2,
                            unsigned char* __restrict__ msel, int* tie_cnt, int* tie_idx)
{
  const uint T = res2[0];
  for (int i = blockIdx.x * blockDim.x + threadIdx.x; i < NOUTC; i += gridDim.x * blockDim.x) {
    uint key = fkey(cls[i]);
    msel[i] = key > T ? 1 : 0;
    if (key == T) {
      int p = atomicAdd(tie_cnt, 1);
      if (p < 4096) tie_idx[p] = i;
    }
  }
}

__global__ void tie_kernel(const uint* __restrict__ res2, const int* __restrict__ tie_cnt,
                           const int* __restrict__ tie_idx, unsigned char* __restrict__ msel)
{
  int need = (int)res2[1];
  int cnt = tie_cnt[0]; if (cnt > 4096) cnt = 4096;
  if (need <= 0) return;
  if (cnt <= need) {
    for (int i = threadIdx.x; i < cnt; i += 256) msel[tie_idx[i]] = 1;
  } else {
    for (int i = threadIdx.x; i < cnt; i += 256) {
      int my = tie_idx[i];
      int rank = 0;
      for (int j = 0; j < cnt; ++j) rank += (tie_idx[j] < my) ? 1 : 0;
      if (rank < need) msel[my] = 1;
    }
  }
}

__global__ void prune_kernel(const float* __restrict__ feats, const unsigned char* __restrict__ msel,
                             const void* __restrict__ mtrue, const int* __restrict__ flag,
                             float* __restrict__ dout)
{
  const unsigned char* mb = (const unsigned char*)mtrue;
  const int* mi = (const int*)mtrue;
  const bool bytes = (flag[0] != 0);
  float* pruned = dout + NOUTC;
  float* maskf  = dout + NOUTC + (size_t)NOUTC * 64;
  const float4* src = reinterpret_cast<const float4*>(feats);
  float4* dst = reinterpret_cast<float4*>(pruned);
  const int total = NOUTC * 16;
  for (int i = blockIdx.x * blockDim.x + threadIdx.x; i < total; i += gridDim.x * blockDim.x) {
    int n = i >> 4;
    bool mt = bytes ? (mb[n] != 0) : (mi[n] != 0);
    bool m = (msel[n] != 0) || mt;
    float4 v = src[i];
    float4 z = {0.f, 0.f, 0.f, 0.f};
    dst[i] = m ? v : z;
    if ((i & 15) == 0) maskf[n] = m ? 1.f : 0.f;
  }
}

// ---------------------------------------------------------------------------
extern "C" void kernel_launch(void* const* d_in, const int* in_sizes, int n_in,
                              void* d_out, int out_size, void* d_ws, size_t ws_size,
                              hipStream_t stream)
{
  const float* x    = (const float*)d_in[0];
  const float* Wup  = (const float*)d_in[1];
  const float* bup  = (const float*)d_in[2];
  const float* Wc0  = (const float*)d_in[3];
  const float* bc0  = (const float*)d_in[4];
  const float* W00  = (const float*)d_in[5];
  const float* b00  = (const float*)d_in[6];
  const float* W01  = (const float*)d_in[7];
  const float* b01  = (const float*)d_in[8];
  const float* W10  = (const float*)d_in[9];
  const float* b10  = (const float*)d_in[10];
  const float* W11  = (const float*)d_in[11];
  const float* b11  = (const float*)d_in[12];
  const float* W12  = (const float*)d_in[13];
  const float* b12  = (const float*)d_in[14];
  const float* Wcls = (const float*)d_in[15];
  const float* bcls = (const float*)d_in[16];
  const int*   nbr  = (const int*)d_in[17];
  const void*  mtrue= d_in[18];
  const int*   nums = (const int*)d_in[19];

  float* dout = (float*)d_out;

  float* fa   = (float*)d_ws;                               // (N+1)*64
  float* t0   = fa + (size_t)(NOUTC + 1) * 64;              // (N+1)*16
  float* t1   = t0 + (size_t)(NOUTC + 1) * 16;              // (N+1)*16
  float* g    = t0;                                         // cls overlay (dead by then)
  float* slab = t1 + (size_t)(NOUTC + 1) * 16;              // CAP*32 floats
  uint*  hist1 = (uint*)(slab + (size_t)CAP * 32);
  uint*  hist2 = hist1 + 65536;
  uint*  res1  = hist2 + 65536;
  uint*  res2  = res1 + 2;
  int*   tie_cnt = (int*)(res2 + 2);
  int*   flag    = tie_cnt + 1;
  int*   tie_idx = flag + 1;                                // 4096
  uint*  counts  = (uint*)(tie_idx + 4096);                 // 3456
  uint*  choff   = counts + 27 * NCH;                       // 3456
  int*   karr    = (int*)(choff + 27 * NCH);                // MAXB
  int*   meta    = karr + MAXB;                             // pad
  uint2* entries = (uint2*)(meta + 4);                      // CAP
  unsigned char* msel = (unsigned char*)(entries + CAP);    // NOUTC bytes
  float* WW   = (float*)(msel + NOUTC);                     // 262144 floats
  float* WW2  = WW + 262144;                                // 3 * 131072 floats
  float* fb = dout + NOUTC;   // (N+1)*64 parked in d_out's pruned+mask region

  init_kernel<<<512, 256, 0, stream>>>(hist1, hist2, tie_cnt, flag, fa, fb, t0, t1);
  detect_kernel<<<128, 256, 0, stream>>>((const unsigned char*)mtrue, flag);

  // build sparse-entry lists + expanded sib weight matrices
  hipMemsetAsync(entries, 0xFF, (size_t)CAP * sizeof(uint2), stream);
  count_kernel<<<27 * NCH, 256, 0, stream>>>(nbr, counts);
  scan_kernel<<<1, 256, 0, stream>>>(counts, choff, karr);
  fill_kernel<<<27 * NCH, 256, 0, stream>>>(nbr, choff, entries);
  ww_prep_c0<<<1024, 256, 0, stream>>>(Wc0, WW);
  for (int i = 0; i < 3; ++i)
    ww_prep_a2<<<512, 256, 0, stream>>>(W00 + (size_t)i * 27 * 1024,
                                        W10 + (size_t)i * 1024,
                                        WW2 + (size_t)i * 131072);

  upsample_kernel<<<2048, 256, 0, stream>>>(x, Wup, bup, fa);

  // c0 = relu(sibGEMM + sparse + bc0)
  gemm_ww2<8, 63, false><<<1024, 256, 0, stream>>>(fa, WW, bc0, nullptr, fb, nullptr, 512);
  p1c0_kernel<<<MAXB, 128, 0, stream>>>(fa, Wc0, entries, karr, slab, 0);
  cmbc0_kernel<<<256, 256, 0, stream>>>(nbr, choff, slab, fb, 0);
  p1c0_kernel<<<MAXB, 128, 0, stream>>>(fa, Wc0, entries, karr, slab, 1);
  cmbc0_kernel<<<256, 256, 0, stream>>>(nbr, choff, slab, fb, 1);

  const float* cur = fb; float* nxt = fa;
  for (int i = 0; i < 3; ++i) {
    const float* W00i = W00 + (size_t)i * 27 * 1024;
    // t0 = sibGEMM(W00)+b00 (pre-sparse), t1 = relu(cur@W10+b10) — one GEMM
    gemm_ww2<4, 15, true><<<1024, 256, 0, stream>>>(cur, WW2 + (size_t)i * 131072,
                                                    b00 + i * 16, b10 + i * 16,
                                                    t0, t1, 256);
    p1a_kernel<<<MAXB, 128, 0, stream>>>(cur, W00i, entries, karr, slab);
    cmba_kernel<<<128, 256, 0, stream>>>(nbr, choff, slab, t0);
    // nxt[:,0:32] = spconv(t0, W01) + b01 + cur[:,0:32]
    spconv2<128, 16, 32, 4, 256, 27, false, false, true>
        <<<NOUTC / 128, 256, 0, stream>>>(t0, nbr, W01 + (size_t)i * 27 * 512,
                                          b01 + i * 32, cur, nxt, 64, 0);
    // t0 = relu(spconv(t1, W11) + b11)
    spconv2<128, 16, 16, 4, 128, 27, false, true, false>
        <<<NOUTC / 128, 128, 0, stream>>>(t1, nbr, W11 + (size_t)i * 27 * 256,
                                          b11 + i * 16, nullptr, t0, 16, 0);
    // nxt[:,32:64] = t0 @ W12 + b12 + cur[:,32:64]
    spconv2<128, 16, 32, 4, 256, 1, true, false, true>
        <<<NOUTC / 128, 256, 0, stream>>>(t0, nullptr, W12 + (size_t)i * 512,
                                          b12 + i * 32, cur, nxt, 64, 32);
    float* tmp = (float*)cur; cur = nxt; nxt = tmp;
  }
  // final features in fa

  cls1_kernel<<<512, 256, 0, stream>>>(cur, Wcls, g);
  cls2_kernel<<<512, 256, 0, stream>>>(g, nbr, bcls, dout);

  hist1_kernel<<<512, 256, 0, stream>>>(dout, hist1);
  scan1_kernel<<<1, 256, 0, stream>>>(hist1, nums, res1);
  hist2_kernel<<<512, 256, 0, stream>>>(dout, res1, hist2);
  scan2_kernel<<<1, 256, 0, stream>>>(hist2, res1, nums, res2);
  mark_kernel<<<512, 256, 0, stream>>>(dout, res2, msel, tie_cnt, tie_idx);
  tie_kernel<<<1, 256, 0, stream>>>(res2, tie_cnt, tie_idx, msel);
  prune_kernel<<<4096, 256, 0, stream>>>(cur, msel, mtrue, flag, dout);
}